// Round 5
// baseline (929.074 us; speedup 1.0000x reference)
//
#include <hip/hip_runtime.h>
#include <hip/hip_bf16.h>
#include <math.h>

#define T_    2048
#define HID_  1024
#define NH_   16
#define NKV_  4
#define HD_   64
#define E_    8
#define TOPK_ 2
#define INTER_ 3584
#define EPS_  1e-6f

typedef __attribute__((ext_vector_type(8))) short short8;
typedef __attribute__((ext_vector_type(4))) float floatx4;

__device__ inline short f2bf(float f) {
    __hip_bfloat16 b = __float2bfloat16(f);
    return *reinterpret_cast<short*>(&b);
}

__device__ inline void cvt_store16(short* dst, float4 a, float4 b, float4 c, float4 d) {
    short8 lo, hi;
    lo[0] = f2bf(a.x); lo[1] = f2bf(a.y); lo[2] = f2bf(a.z); lo[3] = f2bf(a.w);
    lo[4] = f2bf(b.x); lo[5] = f2bf(b.y); lo[6] = f2bf(b.z); lo[7] = f2bf(b.w);
    hi[0] = f2bf(c.x); hi[1] = f2bf(c.y); hi[2] = f2bf(c.z); hi[3] = f2bf(c.w);
    hi[4] = f2bf(d.x); hi[5] = f2bf(d.y); hi[6] = f2bf(d.z); hi[7] = f2bf(d.w);
    *(short8*)dst = lo;
    *(short8*)(dst + 8) = hi;
}

// async global->LDS, 16B per lane. LDS dest must be wave-uniform-base + lane*16.
__device__ inline void async_copy16(short* lds, const short* g) {
    __builtin_amdgcn_global_load_lds((const __attribute__((address_space(1))) void*)g,
                                     (__attribute__((address_space(3))) void*)lds, 16, 0, 0);
}

// ---------------- RMSNorm: one block (256 thr) per row ----------------
__global__ __launch_bounds__(256) void rmsnorm_kernel(const float* __restrict__ x,
                                                      const float* __restrict__ w,
                                                      float* __restrict__ o) {
    int t = blockIdx.x;
    const float* xr = x + (size_t)t * HID_;
    float s = 0.f;
    for (int d = threadIdx.x; d < HID_; d += 256) { float v = xr[d]; s += v * v; }
    __shared__ float red[256];
    red[threadIdx.x] = s; __syncthreads();
    for (int off = 128; off > 0; off >>= 1) {
        if (threadIdx.x < off) red[threadIdx.x] += red[threadIdx.x + off];
        __syncthreads();
    }
    float inv = rsqrtf(red[0] / (float)HID_ + EPS_);
    for (int d = threadIdx.x; d < HID_; d += 256)
        o[(size_t)t * HID_ + d] = w[d] * xr[d] * inv;
}

// ---------------- Generic fp32 GEMM (fallback path only) ----------------
__global__ __launch_bounds__(256) void gemm_f32(const float* __restrict__ A,
                                                const float* __restrict__ B,
                                                float* __restrict__ C,
                                                const float* __restrict__ addsrc,
                                                int M, int N, int K) {
    __shared__ float As[16][65];
    __shared__ float Bs[16][65];
    int tid = threadIdx.x;
    int tx = tid & 15, ty = tid >> 4;
    int bm = blockIdx.y * 64, bn = blockIdx.x * 64;
    float acc[4][4];
#pragma unroll
    for (int i = 0; i < 4; i++)
#pragma unroll
        for (int j = 0; j < 4; j++) acc[i][j] = 0.f;

    int mL[4], kL[4];
#pragma unroll
    for (int l = 0; l < 4; l++) { int idx = tid + l * 256; mL[l] = idx >> 4; kL[l] = idx & 15; }

    for (int k0 = 0; k0 < K; k0 += 16) {
#pragma unroll
        for (int l = 0; l < 4; l++) {
            int m = mL[l], kk = kL[l];
            int gr = bm + m;
            As[kk][m] = (gr < M) ? A[(size_t)gr * K + k0 + kk] : 0.f;
            int gc = bn + m;
            Bs[kk][m] = (gc < N) ? B[(size_t)gc * K + k0 + kk] : 0.f;
        }
        __syncthreads();
#pragma unroll
        for (int kk = 0; kk < 16; kk++) {
            float a[4], b[4];
#pragma unroll
            for (int i = 0; i < 4; i++) a[i] = As[kk][ty * 4 + i];
#pragma unroll
            for (int j = 0; j < 4; j++) b[j] = Bs[kk][tx * 4 + j];
#pragma unroll
            for (int i = 0; i < 4; i++)
#pragma unroll
                for (int j = 0; j < 4; j++) acc[i][j] += a[i] * b[j];
        }
        __syncthreads();
    }
#pragma unroll
    for (int i = 0; i < 4; i++) {
        int r = bm + ty * 4 + i;
        if (r >= M) continue;
#pragma unroll
        for (int j = 0; j < 4; j++) {
            int c = bn + tx * 4 + j;
            if (c >= N) continue;
            float v = acc[i][j];
            if (addsrc) v += addsrc[(size_t)r * N + c];
            C[(size_t)r * N + c] = v;
        }
    }
}

// ---------------- bf16 MFMA GEMM: C[M,N] = A[M,K] @ B[N,K]^T (+addsrc), fp32 out ----------------
__global__ __launch_bounds__(256, 2) void gemm_bf16_v2(const short* __restrict__ A,
                                                       const short* __restrict__ B,
                                                       float* __restrict__ C,
                                                       const float* __restrict__ addsrc,
                                                       int M, int N, int K) {
    int bm = blockIdx.y * 128;
    int bn = blockIdx.x * 128;

    __shared__ alignas(16) short lds[2][2][128 * 32];  // 32 KiB

    int tid = threadIdx.x;
    int sr = tid >> 2;
    int sc = (tid & 3) * 8;
    int ldst = tid * 8;

    const short* aG0 = A + (size_t)(bm + sr) * K + sc;
    const short* aG1 = aG0 + (size_t)64 * K;
    const short* bG0 = B + (size_t)(bn + sr) * K + sc;
    const short* bG1 = bG0 + (size_t)64 * K;

    int wvid = tid >> 6, lane = tid & 63;
    int wm = (wvid >> 1) * 64, wn = (wvid & 1) * 64;
    int l15 = lane & 15, quad = lane >> 4;

    floatx4 acc[4][4];
#pragma unroll
    for (int i = 0; i < 4; i++)
#pragma unroll
        for (int j = 0; j < 4; j++) acc[i][j] = (floatx4)0.f;

#define STAGEG(b, k0) do {                                          \
        async_copy16(&lds[b][0][ldst],        aG0 + (k0));          \
        async_copy16(&lds[b][0][ldst + 2048], aG1 + (k0));          \
        async_copy16(&lds[b][1][ldst],        bG0 + (k0));          \
        async_copy16(&lds[b][1][ldst + 2048], bG1 + (k0));          \
    } while (0)

    STAGEG(0, 0);
    __syncthreads();

    int cur = 0;
    for (int k0 = 0; k0 < K; k0 += 32) {
        if (k0 + 32 < K) STAGEG(cur ^ 1, k0 + 32);

        const short* XaR = &lds[cur][0][(wm + l15) * 32 + quad * 8];
        const short* WsR = &lds[cur][1][(wn + l15) * 32 + quad * 8];
        short8 af[4], bf_[4];
#pragma unroll
        for (int i = 0; i < 4; i++) af[i] = *(const short8*)(XaR + i * 16 * 32);
#pragma unroll
        for (int j = 0; j < 4; j++) bf_[j] = *(const short8*)(WsR + j * 16 * 32);
#pragma unroll
        for (int i = 0; i < 4; i++)
#pragma unroll
            for (int j = 0; j < 4; j++)
                acc[i][j] = __builtin_amdgcn_mfma_f32_16x16x32_bf16(af[i], bf_[j], acc[i][j], 0, 0, 0);
        __syncthreads();
        cur ^= 1;
    }
#undef STAGEG

#pragma unroll
    for (int i = 0; i < 4; i++) {
#pragma unroll
        for (int reg = 0; reg < 4; reg++) {
            int r = bm + wm + i * 16 + quad * 4 + reg;
            size_t rowoff = (size_t)r * N;
#pragma unroll
            for (int j = 0; j < 4; j++) {
                int c = bn + wn + j * 16 + l15;
                float v = acc[i][j][reg];
                if (addsrc) v += addsrc[rowoff + c];
                C[rowoff + c] = v;
            }
        }
    }
}

// ---------------- RoPE in-place on q and k ----------------
__global__ void rope_kernel(float* __restrict__ qb, float* __restrict__ kb,
                            const int* __restrict__ pos_ids) {
    int idx = blockIdx.x * blockDim.x + threadIdx.x;
    const int totq = T_ * NH_ * 32;
    const int totk = T_ * NKV_ * 32;
    if (idx >= totq + totk) return;
    float* buf; int t, hh, i, hw;
    if (idx < totq) { buf = qb; hw = NH_;  t = idx / (NH_ * 32); int r = idx % (NH_ * 32); hh = r / 32; i = r % 32; }
    else { idx -= totq; buf = kb; hw = NKV_; t = idx / (NKV_ * 32); int r = idx % (NKV_ * 32); hh = r / 32; i = r % 32; }
    float pos = (float)pos_ids[t];
    float inv = expf(-(float)i * (13.815510558f / 32.0f));
    float fr = pos * inv;
    float c = cosf(fr), s = sinf(fr);
    size_t base = (size_t)t * hw * 64 + (size_t)hh * 64;
    float x1 = buf[base + i], x2 = buf[base + i + 32];
    buf[base + i]      = x1 * c - x2 * s;
    buf[base + i + 32] = x2 * c + x1 * s;
}

// ---------------- Flash attention v2: bf16 MFMA, bf16 output ----------------
__global__ __launch_bounds__(256) void flash_attn_mfma(const short* __restrict__ qbh,
                                                       const short* __restrict__ kbh,
                                                       const short* __restrict__ vbh,
                                                       short* __restrict__ obh) {
    __shared__ alignas(16) short Ks[64][80];
    __shared__ alignas(16) short Vt[64][80];
    __shared__ alignas(16) short Ps[64][80];

    int bid = blockIdx.x;
    int h = bid & 15;
    int qr = bid >> 4;
    int qt = (qr & 1) ? (31 - (qr >> 1)) : (qr >> 1);
    int q0 = qt * 64;
    int kvh = h >> 2;
    int tid = threadIdx.x;
    int w = tid >> 6, lane = tid & 63;
    int l15 = lane & 15, quad = lane >> 4;
    int str = tid >> 2, stc = tid & 3;

    short8 aq0, aq1;
    {
        const short* qrow = qbh + (size_t)(q0 + 16 * w + l15) * (NH_ * HD_) + h * HD_ + quad * 8;
        aq0 = *(const short8*)(qrow);
        aq1 = *(const short8*)(qrow + 32);
    }

    floatx4 o_acc[4];
    float m_i[4], l_i[4];
#pragma unroll
    for (int j = 0; j < 4; j++) o_acc[j] = (floatx4)0.f;
#pragma unroll
    for (int r = 0; r < 4; r++) { m_i[r] = -INFINITY; l_i[r] = 0.f; }

    int nt = q0 / 64 + 1;

    const short* kg = kbh + (size_t)str * (NKV_ * HD_) + kvh * HD_ + stc * 8;
    const short* vg = vbh + (size_t)str * (NKV_ * HD_) + kvh * HD_ + stc * 8;
    short8 kr0 = *(const short8*)kg;
    short8 kr1 = *(const short8*)(kg + 32);
    short8 vr0 = *(const short8*)vg;
    short8 vr1 = *(const short8*)(vg + 32);

    for (int it = 0; it < nt; ++it) {
        int t0 = it * 64;
        __syncthreads();
        *(short8*)&Ks[str][stc * 8]      = kr0;
        *(short8*)&Ks[str][32 + stc * 8] = kr1;
#pragma unroll
        for (int i = 0; i < 8; i++) {
            Vt[stc * 8 + i][str]      = vr0[i];
            Vt[32 + stc * 8 + i][str] = vr1[i];
        }
        if (it + 1 < nt) {
            const short* kgn = kbh + (size_t)(t0 + 64 + str) * (NKV_ * HD_) + kvh * HD_ + stc * 8;
            const short* vgn = vbh + (size_t)(t0 + 64 + str) * (NKV_ * HD_) + kvh * HD_ + stc * 8;
            kr0 = *(const short8*)kgn;
            kr1 = *(const short8*)(kgn + 32);
            vr0 = *(const short8*)vgn;
            vr1 = *(const short8*)(vgn + 32);
        }
        __syncthreads();

        floatx4 s[4];
#pragma unroll
        for (int j = 0; j < 4; j++) s[j] = (floatx4)0.f;
        __builtin_amdgcn_s_setprio(1);
#pragma unroll
        for (int j = 0; j < 4; j++) {
            short8 bk0 = *(const short8*)&Ks[16 * j + l15][quad * 8];
            short8 bk1 = *(const short8*)&Ks[16 * j + l15][32 + quad * 8];
            s[j] = __builtin_amdgcn_mfma_f32_16x16x32_bf16(aq0, bk0, s[j], 0, 0, 0);
            s[j] = __builtin_amdgcn_mfma_f32_16x16x32_bf16(aq1, bk1, s[j], 0, 0, 0);
        }
        __builtin_amdgcn_s_setprio(0);

        bool diag = (t0 == q0);
#pragma unroll
        for (int j = 0; j < 4; j++)
#pragma unroll
            for (int reg = 0; reg < 4; reg++) {
                s[j][reg] *= 0.125f;
                if (diag && (16 * j + l15 > 16 * w + quad * 4 + reg)) s[j][reg] = -INFINITY;
            }

#pragma unroll
        for (int reg = 0; reg < 4; reg++) {
            float mx = fmaxf(fmaxf(s[0][reg], s[1][reg]), fmaxf(s[2][reg], s[3][reg]));
#pragma unroll
            for (int off = 8; off >= 1; off >>= 1) mx = fmaxf(mx, __shfl_xor(mx, off));
            float mn = fmaxf(m_i[reg], mx);
            float alpha = __expf(m_i[reg] - mn);
            float rs = 0.f;
#pragma unroll
            for (int j = 0; j < 4; j++) { float p = __expf(s[j][reg] - mn); s[j][reg] = p; rs += p; }
#pragma unroll
            for (int off = 8; off >= 1; off >>= 1) rs += __shfl_xor(rs, off);
            l_i[reg] = l_i[reg] * alpha + rs;
            m_i[reg] = mn;
#pragma unroll
            for (int j = 0; j < 4; j++) o_acc[j][reg] *= alpha;
        }

#pragma unroll
        for (int j = 0; j < 4; j++)
#pragma unroll
            for (int reg = 0; reg < 4; reg++)
                Ps[16 * w + quad * 4 + reg][16 * j + l15] = f2bf(s[j][reg]);
        __asm__ volatile("s_waitcnt lgkmcnt(0)" ::: "memory");

        short8 ap0 = *(const short8*)&Ps[16 * w + l15][quad * 8];
        short8 ap1 = *(const short8*)&Ps[16 * w + l15][32 + quad * 8];
        __builtin_amdgcn_s_setprio(1);
#pragma unroll
        for (int j = 0; j < 4; j++) {
            short8 bv0 = *(const short8*)&Vt[16 * j + l15][quad * 8];
            short8 bv1 = *(const short8*)&Vt[16 * j + l15][32 + quad * 8];
            o_acc[j] = __builtin_amdgcn_mfma_f32_16x16x32_bf16(ap0, bv0, o_acc[j], 0, 0, 0);
            o_acc[j] = __builtin_amdgcn_mfma_f32_16x16x32_bf16(ap1, bv1, o_acc[j], 0, 0, 0);
        }
        __builtin_amdgcn_s_setprio(0);
    }

#pragma unroll
    for (int reg = 0; reg < 4; reg++) {
        float invl = 1.f / l_i[reg];
        size_t rbase = (size_t)(q0 + 16 * w + quad * 4 + reg) * (NH_ * HD_) + h * HD_;
#pragma unroll
        for (int j = 0; j < 4; j++)
            obh[rbase + 16 * j + l15] = f2bf(o_acc[j][reg] * invl);
    }
}

// ---------------- Flash attention (fp32 fallback) ----------------
__global__ __launch_bounds__(256) void flash_attn_kernel(const float* __restrict__ qb,
                                                         const float* __restrict__ kb,
                                                         const float* __restrict__ vb,
                                                         float* __restrict__ ob) {
    __shared__ float Qs[64][68];
    __shared__ float Ks[64][68];
    __shared__ float Vs[64][68];
    __shared__ float Ps[64][68];

    int bid = blockIdx.x;
    int h = bid & 15;
    int qr = bid >> 4;
    int qt = (qr & 1) ? (31 - (qr >> 1)) : (qr >> 1);
    int q0 = qt * 64;
    int kvh = h >> 2;
    int tid = threadIdx.x;
    int tx = tid & 15, ty = tid >> 4;

#pragma unroll
    for (int l = 0; l < 16; l++) {
        int idx = l * 256 + tid;
        int m = idx >> 6, d = idx & 63;
        Qs[d][m] = qb[(size_t)(q0 + m) * (NH_ * HD_) + h * HD_ + d];
    }

    float o_acc[4][4];
    float m_i[4], l_i[4];
#pragma unroll
    for (int i = 0; i < 4; i++) {
        m_i[i] = -INFINITY; l_i[i] = 0.f;
#pragma unroll
        for (int j = 0; j < 4; j++) o_acc[i][j] = 0.f;
    }

    for (int t0 = 0; t0 <= q0; t0 += 64) {
        __syncthreads();
#pragma unroll
        for (int l = 0; l < 16; l++) {
            int idx = l * 256 + tid;
            int m = idx >> 6, d = idx & 63;
            size_t g = (size_t)(t0 + m) * (NKV_ * HD_) + kvh * HD_ + d;
            Ks[d][m] = kb[g];
            Vs[m][d] = vb[g];
        }
        __syncthreads();

        float s[4][4];
#pragma unroll
        for (int i = 0; i < 4; i++)
#pragma unroll
            for (int j = 0; j < 4; j++) s[i][j] = 0.f;
#pragma unroll 4
        for (int kk = 0; kk < 64; kk++) {
            float4 a4 = *(const float4*)&Qs[kk][ty * 4];
            float4 b4 = *(const float4*)&Ks[kk][tx * 4];
            float a[4] = {a4.x, a4.y, a4.z, a4.w};
            float b[4] = {b4.x, b4.y, b4.z, b4.w};
#pragma unroll
            for (int i = 0; i < 4; i++)
#pragma unroll
                for (int j = 0; j < 4; j++) s[i][j] += a[i] * b[j];
        }

        bool diag = (t0 == q0);
#pragma unroll
        for (int i = 0; i < 4; i++) {
#pragma unroll
            for (int j = 0; j < 4; j++) {
                s[i][j] *= 0.125f;
                if (diag && (t0 + tx * 4 + j > q0 + ty * 4 + i)) s[i][j] = -INFINITY;
            }
        }

#pragma unroll
        for (int i = 0; i < 4; i++) {
            float mx = fmaxf(fmaxf(s[i][0], s[i][1]), fmaxf(s[i][2], s[i][3]));
#pragma unroll
            for (int off = 8; off >= 1; off >>= 1) mx = fmaxf(mx, __shfl_xor(mx, off));
            float mn = fmaxf(m_i[i], mx);
            float alpha = __expf(m_i[i] - mn);
            float rs = 0.f;
#pragma unroll
            for (int j = 0; j < 4; j++) { float p = __expf(s[i][j] - mn); s[i][j] = p; rs += p; }
#pragma unroll
            for (int off = 8; off >= 1; off >>= 1) rs += __shfl_xor(rs, off);
            l_i[i] = l_i[i] * alpha + rs;
            m_i[i] = mn;
#pragma unroll
            for (int j = 0; j < 4; j++) o_acc[i][j] *= alpha;
        }

#pragma unroll
        for (int j = 0; j < 4; j++)
#pragma unroll
            for (int i = 0; i < 4; i++)
                Ps[tx * 4 + j][ty * 4 + i] = s[i][j];
        __syncthreads();

#pragma unroll 4
        for (int kk = 0; kk < 64; kk++) {
            float4 a4 = *(const float4*)&Ps[kk][ty * 4];
            float4 b4 = *(const float4*)&Vs[kk][tx * 4];
            float a[4] = {a4.x, a4.y, a4.z, a4.w};
            float b[4] = {b4.x, b4.y, b4.z, b4.w};
#pragma unroll
            for (int i = 0; i < 4; i++)
#pragma unroll
                for (int j = 0; j < 4; j++) o_acc[i][j] += a[i] * b[j];
        }
    }

#pragma unroll
    for (int i = 0; i < 4; i++) {
        float invl = 1.f / l_i[i];
        int r = q0 + ty * 4 + i;
#pragma unroll
        for (int j = 0; j < 4; j++)
            ob[(size_t)r * (NH_ * HD_) + h * HD_ + tx * 4 + j] = o_acc[i][j] * invl;
    }
}

// ---------------- Gating: one wave per token ----------------
__global__ __launch_bounds__(64) void gating_kernel(const float* __restrict__ xn2,
                                                    const float* __restrict__ gate_w,
                                                    int* __restrict__ sel,
                                                    float* __restrict__ wt,
                                                    int* __restrict__ counts) {
    int t = blockIdx.x, lane = threadIdx.x;
    const float* x = xn2 + (size_t)t * HID_;
    float logits[E_];
    for (int e = 0; e < E_; e++) {
        float p = 0.f;
        for (int d = lane; d < HID_; d += 64) p += x[d] * gate_w[(size_t)e * HID_ + d];
#pragma unroll
        for (int off = 32; off > 0; off >>= 1) p += __shfl_xor(p, off);
        logits[e] = p;
    }
    float mx = logits[0];
    for (int e = 1; e < E_; e++) mx = fmaxf(mx, logits[e]);
    float pr[E_]; float sum = 0.f;
    for (int e = 0; e < E_; e++) { pr[e] = __expf(logits[e] - mx); sum += pr[e]; }
    int e1 = 0; float p1 = pr[0];
    for (int e = 1; e < E_; e++) if (pr[e] > p1) { p1 = pr[e]; e1 = e; }
    int e2 = -1; float p2 = -1.f;
    for (int e = 0; e < E_; e++) if (e != e1 && pr[e] > p2) { p2 = pr[e]; e2 = e; }
    if (lane == 0) {
        float denom = p1 + p2;
        sel[t * 2] = e1; sel[t * 2 + 1] = e2;
        wt[t * 2] = p1 / denom; wt[t * 2 + 1] = p2 / denom;
        atomicAdd(&counts[e1], 1);
        atomicAdd(&counts[e2], 1);
    }
}

__global__ void init_counts_kernel(int* counts) {
    if (threadIdx.x < E_) counts[threadIdx.x] = 0;
}

__global__ void prefix_kernel(const int* __restrict__ counts, int* __restrict__ ebase,
                              int* __restrict__ cursor) {
    if (threadIdx.x == 0) {
        int b = 0;
        for (int e = 0; e < E_; e++) { ebase[e] = b; cursor[e] = b; b += counts[e]; }
    }
}

__global__ void scatter_kernel(const int* __restrict__ sel, const float* __restrict__ wt,
                               int* __restrict__ cursor, int* __restrict__ tok_list,
                               float* __restrict__ wt_list) {
    int t = blockIdx.x * blockDim.x + threadIdx.x;
    if (t >= T_) return;
    for (int j = 0; j < 2; j++) {
        int e = sel[t * 2 + j];
        float w = wt[t * 2 + j];
        int p = atomicAdd(&cursor[e], 1);
        tok_list[p] = t;
        wt_list[p] = w;
    }
}

// ---------------- fp32 -> bf16 bulk convert (RNE, memory-bound) ----------------
__global__ __launch_bounds__(256) void cvt_bf16_kernel(const float* __restrict__ src,
                                                       short* __restrict__ dst, int n8) {
    int stride = gridDim.x * blockDim.x;
    for (int i = blockIdx.x * blockDim.x + threadIdx.x; i < n8; i += stride) {
        float4 a = ((const float4*)src)[2 * i];
        float4 b = ((const float4*)src)[2 * i + 1];
        short8 o;
        o[0] = f2bf(a.x); o[1] = f2bf(a.y); o[2] = f2bf(a.z); o[3] = f2bf(a.w);
        o[4] = f2bf(b.x); o[5] = f2bf(b.y); o[6] = f2bf(b.z); o[7] = f2bf(b.w);
        ((short8*)dst)[i] = o;
    }
}

// ---------------- MoE GEMM 1&3 v3: 256Mx128N tile, 512 thr / 8 waves ----------------
// Wave grid 4Mx2N; per-wave output 64x64 for acc1 AND acc3 (2x16 floatx4 = 128 VGPR).
// Cuts B(w1,w3)-panel re-reads 2x vs the 128-tile version (traffic 1.34GB -> 0.92GB).
__global__ __launch_bounds__(512, 2) void moe_gemm13_v3(const short* __restrict__ Xb,
                                                        const short* __restrict__ w1b,
                                                        const short* __restrict__ w3b,
                                                        const int* __restrict__ tok_list,
                                                        const int* __restrict__ ebase,
                                                        const int* __restrict__ counts,
                                                        __hip_bfloat16* __restrict__ h13b) {
    int e = blockIdx.z;
    int cnt = counts[e];
    int bm = blockIdx.y * 256;
    if (cnt <= 0 || bm >= cnt) return;
    int base = ebase[e];
    int bn = blockIdx.x * 128;

    __shared__ alignas(16) short ldsA[2][256 * 32];   // 32 KiB
    __shared__ alignas(16) short ldsB1[2][128 * 32];  // 16 KiB
    __shared__ alignas(16) short ldsB3[2][128 * 32];  // 16 KiB

    int tid = threadIdx.x;          // 0..511
    int sr = tid >> 2;              // 0..127
    int sc = (tid & 3) * 8;
    int ldst = tid * 8;             // = sr*32 + sc

    int lr0 = bm + sr, lr1 = bm + sr + 128;
    int tok0 = tok_list[base + (lr0 < cnt ? lr0 : cnt - 1)];
    int tok1 = tok_list[base + (lr1 < cnt ? lr1 : cnt - 1)];
    const short* aG0 = Xb + (size_t)tok0 * HID_ + sc;
    const short* aG1 = Xb + (size_t)tok1 * HID_ + sc;
    const short* b1G = w1b + (size_t)e * INTER_ * HID_ + (size_t)(bn + sr) * HID_ + sc;
    const short* b3G = w3b + (size_t)e * INTER_ * HID_ + (size_t)(bn + sr) * HID_ + sc;

    int wvid = tid >> 6, lane = tid & 63;
    int wm = (wvid >> 1) * 64, wn = (wvid & 1) * 64;
    int l15 = lane & 15, quad = lane >> 4;

    floatx4 acc1[4][4], acc3[4][4];
#pragma unroll
    for (int i = 0; i < 4; i++)
#pragma unroll
        for (int j = 0; j < 4; j++) { acc1[i][j] = (floatx4)0.f; acc3[i][j] = (floatx4)0.f; }

#define STAGE13(b, k0) do {                                     \
        async_copy16(&ldsA[b][ldst],        aG0 + (k0));        \
        async_copy16(&ldsA[b][ldst + 4096], aG1 + (k0));        \
        async_copy16(&ldsB1[b][ldst],       b1G + (k0));        \
        async_copy16(&ldsB3[b][ldst],       b3G + (k0));        \
    } while (0)

    STAGE13(0, 0);
    __syncthreads();

    int cur = 0;
    for (int k0 = 0; k0 < HID_; k0 += 32) {
        if (k0 + 32 < HID_) STAGE13(cur ^ 1, k0 + 32);

        const short* XaR = &ldsA[cur][(wm + l15) * 32 + quad * 8];
        const short* W1r = &ldsB1[cur][(wn + l15) * 32 + quad * 8];
        const short* W3r = &ldsB3[cur][(wn + l15) * 32 + quad * 8];
        short8 af[4], b1f[4], b3f[4];
#pragma unroll
        for (int i = 0; i < 4; i++) af[i] = *(const short8*)(XaR + i * 16 * 32);
#pragma unroll
        for (int j = 0; j < 4; j++) {
            b1f[j] = *(const short8*)(W1r + j * 16 * 32);
            b3f[j] = *(const short8*)(W3r + j * 16 * 32);
        }
#pragma unroll
        for (int i = 0; i < 4; i++)
#pragma unroll
            for (int j = 0; j < 4; j++) {
                acc1[i][j] = __builtin_amdgcn_mfma_f32_16x16x32_bf16(af[i], b1f[j], acc1[i][j], 0, 0, 0);
                acc3[i][j] = __builtin_amdgcn_mfma_f32_16x16x32_bf16(af[i], b3f[j], acc3[i][j], 0, 0, 0);
            }
        __syncthreads();
        cur ^= 1;
    }
#undef STAGE13

#pragma unroll
    for (int i = 0; i < 4; i++) {
#pragma unroll
        for (int reg = 0; reg < 4; reg++) {
            int lrow = bm + wm + i * 16 + quad * 4 + reg;
            if (lrow >= cnt) continue;
            size_t rowoff = (size_t)(base + lrow) * INTER_;
#pragma unroll
            for (int j = 0; j < 4; j++) {
                float a = acc1[i][j][reg];
                float v = (a / (1.f + __expf(-a))) * acc3[i][j][reg];
                h13b[rowoff + bn + wn + j * 16 + l15] = __float2bfloat16(v);
            }
        }
    }
}

// ---------------- MoE GEMM 2 v3: 256x256 tile, split-K=2, 512 thr / 8 waves ----------------
// Wave grid 2Mx4N; per-wave output 128x64 (32 floatx4 = 128 VGPR). Output is atomicAdd
// so split-K is free. Panel re-reads halve vs 128-tile (traffic 940MB -> 470MB).
__global__ __launch_bounds__(512, 2) void moe_gemm2_v3(const short* __restrict__ h13s,
                                                       const short* __restrict__ w2b,
                                                       const int* __restrict__ tok_list,
                                                       const float* __restrict__ wt_list,
                                                       const int* __restrict__ ebase,
                                                       const int* __restrict__ counts,
                                                       float* __restrict__ out) {
    int zz = blockIdx.z;
    int e = zz >> 1, ks = zz & 1;
    int cnt = counts[e];
    int bm = blockIdx.y * 256;
    if (cnt <= 0 || bm >= cnt) return;
    int base = ebase[e];
    int bn = blockIdx.x * 256;
    const int K0 = ks * (INTER_ / 2);     // split-K half: 1792

    __shared__ alignas(16) short lds[2][2][256 * 32];  // 64 KiB

    int tid = threadIdx.x;          // 0..511
    int sr = tid >> 2;              // 0..127
    int sc = (tid & 3) * 8;
    int ldst = tid * 8;

    int lr0 = bm + sr, lr1 = bm + sr + 128;
    int slot0 = base + (lr0 < cnt ? lr0 : cnt - 1);
    int slot1 = base + (lr1 < cnt ? lr1 : cnt - 1);
    const short* aG0 = h13s + (size_t)slot0 * INTER_ + K0 + sc;
    const short* aG1 = h13s + (size_t)slot1 * INTER_ + K0 + sc;
    const short* bG0 = w2b + (size_t)e * HID_ * INTER_ + (size_t)(bn + sr) * INTER_ + K0 + sc;
    const short* bG1 = bG0 + (size_t)128 * INTER_;

    int wvid = tid >> 6, lane = tid & 63;
    int wm = (wvid >> 2) * 128, wn = (wvid & 3) * 64;
    int l15 = lane & 15, quad = lane >> 4;

    floatx4 acc[8][4];
#pragma unroll
    for (int i = 0; i < 8; i++)
#pragma unroll
        for (int j = 0; j < 4; j++) acc[i][j] = (floatx4)0.f;

#define STAGE2(b, k0) do {                                      \
        async_copy16(&lds[b][0][ldst],        aG0 + (k0));      \
        async_copy16(&lds[b][0][ldst + 4096], aG1 + (k0));      \
        async_copy16(&lds[b][1][ldst],        bG0 + (k0));      \
        async_copy16(&lds[b][1][ldst + 4096], bG1 + (k0));      \
    } while (0)

    STAGE2(0, 0);
    __syncthreads();

    int cur = 0;
    for (int k0 = 0; k0 < INTER_ / 2; k0 += 32) {
        if (k0 + 32 < INTER_ / 2) STAGE2(cur ^ 1, k0 + 32);

        const short* XaR = &lds[cur][0][(wm + l15) * 32 + quad * 8];
        const short* WsR = &lds[cur][1][(wn + l15) * 32 + quad * 8];
        short8 af[8], bf_[4];
#pragma unroll
        for (int i = 0; i < 8; i++) af[i] = *(const short8*)(XaR + i * 16 * 32);
#pragma unroll
        for (int j = 0; j < 4; j++) bf_[j] = *(const short8*)(WsR + j * 16 * 32);
#pragma unroll
        for (int i = 0; i < 8; i++)
#pragma unroll
            for (int j = 0; j < 4; j++)
                acc[i][j] = __builtin_amdgcn_mfma_f32_16x16x32_bf16(af[i], bf_[j], acc[i][j], 0, 0, 0);
        __syncthreads();
        cur ^= 1;
    }
#undef STAGE2

#pragma unroll
    for (int i = 0; i < 8; i++) {
#pragma unroll
        for (int reg = 0; reg < 4; reg++) {
            int lrow = bm + wm + i * 16 + quad * 4 + reg;
            if (lrow >= cnt) continue;
            int tok = tok_list[base + lrow];
            float w = wt_list[base + lrow];
            size_t rowoff = (size_t)tok * HID_;
#pragma unroll
            for (int j = 0; j < 4; j++)
                atomicAdd(&out[rowoff + bn + wn + j * 16 + l15], w * acc[i][j][reg]);
        }
    }
}

// ---------------- Fallback (old) MoE kernels ----------------
__global__ __launch_bounds__(256) void moe_gemm13_mfma(const float* __restrict__ X,
                                                       const float* __restrict__ w1,
                                                       const float* __restrict__ w3,
                                                       const int* __restrict__ tok_list,
                                                       const int* __restrict__ ebase,
                                                       const int* __restrict__ counts,
                                                       __hip_bfloat16* __restrict__ h13b) {
    int e = blockIdx.z;
    int cnt = counts[e];
    int bm = blockIdx.y * 128;
    if (bm >= cnt) return;
    int base = ebase[e];
    int bn = blockIdx.x * 128;

    __shared__ alignas(16) short Xa[128 * 40];
    __shared__ alignas(16) short W1s[128 * 40];
    __shared__ alignas(16) short W3s[128 * 40];

    int tid = threadIdx.x;
    int sr = tid >> 1;
    int scb = (tid & 1) * 16;

    int lrA = bm + sr;
    int tok = (lrA < cnt) ? tok_list[base + lrA] : 0;
    const float* Arow  = X + (size_t)tok * HID_ + scb;
    const float* B1row = w1 + (size_t)e * INTER_ * HID_ + (size_t)(bn + sr) * HID_ + scb;
    const float* B3row = w3 + (size_t)e * INTER_ * HID_ + (size_t)(bn + sr) * HID_ + scb;
    short* XaW = Xa  + sr * 40 + scb;
    short* W1w = W1s + sr * 40 + scb;
    short* W3w = W3s + sr * 40 + scb;

    int wvid = tid >> 6, lane = tid & 63;
    int wm = (wvid >> 1) * 64, wn = (wvid & 1) * 64;
    int l15 = lane & 15, quad = lane >> 4;

    const short* XaR = Xa  + (wm + l15) * 40 + quad * 8;
    const short* W1r = W1s + (wn + l15) * 40 + quad * 8;
    const short* W3r = W3s + (wn + l15) * 40 + quad * 8;

    floatx4 acc1[4][4], acc3[4][4];
#pragma unroll
    for (int i = 0; i < 4; i++)
#pragma unroll
        for (int j = 0; j < 4; j++) { acc1[i][j] = (floatx4)0.f; acc3[i][j] = (floatx4)0.f; }

    for (int k0 = 0; k0 < HID_; k0 += 32) {
        float4 f0 = *(const float4*)(Arow + k0);
        float4 f1 = *(const float4*)(Arow + k0 + 4);
        float4 f2 = *(const float4*)(Arow + k0 + 8);
        float4 f3 = *(const float4*)(Arow + k0 + 12);
        float4 g0 = *(const float4*)(B1row + k0);
        float4 g1 = *(const float4*)(B1row + k0 + 4);
        float4 g2 = *(const float4*)(B1row + k0 + 8);
        float4 g3 = *(const float4*)(B1row + k0 + 12);
        float4 h0 = *(const float4*)(B3row + k0);
        float4 h1 = *(const float4*)(B3row + k0 + 4);
        float4 h2 = *(const float4*)(B3row + k0 + 8);
        float4 h3 = *(const float4*)(B3row + k0 + 12);
        cvt_store16(XaW, f0, f1, f2, f3);
        cvt_store16(W1w, g0, g1, g2, g3);
        cvt_store16(W3w, h0, h1, h2, h3);
        __syncthreads();

        short8 af[4], b1f[4], b3f[4];
#pragma unroll
        for (int i = 0; i < 4; i++) af[i] = *(const short8*)(XaR + i * 16 * 40);
#pragma unroll
        for (int j = 0; j < 4; j++) {
            b1f[j] = *(const short8*)(W1r + j * 16 * 40);
            b3f[j] = *(const short8*)(W3r + j * 16 * 40);
        }
#pragma unroll
        for (int i = 0; i < 4; i++)
#pragma unroll
            for (int j = 0; j < 4; j++) {
                acc1[i][j] = __builtin_amdgcn_mfma_f32_16x16x32_bf16(af[i], b1f[j], acc1[i][j], 0, 0, 0);
                acc3[i][j] = __builtin_amdgcn_mfma_f32_16x16x32_bf16(af[i], b3f[j], acc3[i][j], 0, 0, 0);
            }
        __syncthreads();
    }

#pragma unroll
    for (int i = 0; i < 4; i++) {
#pragma unroll
        for (int reg = 0; reg < 4; reg++) {
            int lrow = bm + wm + i * 16 + quad * 4 + reg;
            if (lrow >= cnt) continue;
            size_t rowoff = (size_t)(base + lrow) * INTER_;
#pragma unroll
            for (int j = 0; j < 4; j++) {
                float a = acc1[i][j][reg];
                float v = (a / (1.f + __expf(-a))) * acc3[i][j][reg];
                h13b[rowoff + bn + wn + j * 16 + l15] = __float2bfloat16(v);
            }
        }
    }
}

__global__ __launch_bounds__(256) void moe_gemm2_mfma(const __hip_bfloat16* __restrict__ h13b,
                                                      const float* __restrict__ w2,
                                                      const int* __restrict__ tok_list,
                                                      const float* __restrict__ wt_list,
                                                      const int* __restrict__ ebase,
                                                      const int* __restrict__ counts,
                                                      float* __restrict__ out) {
    int e = blockIdx.z;
    int cnt = counts[e];
    int bm = blockIdx.y * 128;
    if (bm >= cnt) return;
    int base = ebase[e];
    int bn = blockIdx.x * 128;

    __shared__ alignas(16) short Xa[128 * 40];
    __shared__ alignas(16) short Ws[128 * 40];

    int tid = threadIdx.x;
    int sr = tid >> 1;
    int scb = (tid & 1) * 16;

    int lrA = bm + sr;
    int slot = base + ((lrA < cnt) ? lrA : 0);
    const short* Arow = (const short*)h13b + (size_t)slot * INTER_ + scb;
    const float* Brow = w2 + (size_t)e * HID_ * INTER_ + (size_t)(bn + sr) * INTER_ + scb;
    short* XaW = Xa + sr * 40 + scb;
    short* WsW = Ws + sr * 40 + scb;

    int wvid = tid >> 6, lane = tid & 63;
    int wm = (wvid >> 1) * 64, wn = (wvid & 1) * 64;
    int l15 = lane & 15, quad = lane >> 4;

    const short* XaR = Xa + (wm + l15) * 40 + quad * 8;
    const short* WsR = Ws + (wn + l15) * 40 + quad * 8;

    floatx4 acc[4][4];
#pragma unroll
    for (int i = 0; i < 4; i++)
#pragma unroll
        for (int j = 0; j < 4; j++) acc[i][j] = (floatx4)0.f;

    for (int k0 = 0; k0 < INTER_; k0 += 32) {
        short8 v0 = *(const short8*)(Arow + k0);
        short8 v1 = *(const short8*)(Arow + k0 + 8);
        float4 g0 = *(const float4*)(Brow + k0);
        float4 g1 = *(const float4*)(Brow + k0 + 4);
        float4 g2 = *(const float4*)(Brow + k0 + 8);
        float4 g3 = *(const float4*)(Brow + k0 + 12);
        *(short8*)XaW = v0;
        *(short8*)(XaW + 8) = v1;
        cvt_store16(WsW, g0, g1, g2, g3);
        __syncthreads();

        short8 af[4], bf_[4];
#pragma unroll
        for (int i = 0; i < 4; i++) af[i] = *(const short8*)(XaR + i * 16 * 40);
#pragma unroll
        for (int j = 0; j < 4; j++) bf_[j] = *(const short8*)(WsR + j * 16 * 40);
#pragma unroll
        for (int i = 0; i < 4; i++)
#pragma unroll
            for (int j = 0; j < 4; j++)
                acc[i][j] = __builtin_amdgcn_mfma_f32_16x16x32_bf16(af[i], bf_[j], acc[i][j], 0, 0, 0);
        __syncthreads();
    }

#pragma unroll
    for (int i = 0; i < 4; i++) {
#pragma unroll
        for (int reg = 0; reg < 4; reg++) {
            int lrow = bm + wm + i * 16 + quad * 4 + reg;
            if (lrow >= cnt) continue;
            int tok = tok_list[base + lrow];
            float w = wt_list[base + lrow];
            size_t rowoff = (size_t)tok * HID_;
#pragma unroll
            for (int j = 0; j < 4; j++)
                atomicAdd(&out[rowoff + bn + wn + j * 16 + l15], w * acc[i][j][reg]);
        }
    }
}

__global__ void copy4_kernel(const float* __restrict__ src, float* __restrict__ dst, int n4) {
    int i = blockIdx.x * blockDim.x + threadIdx.x;
    if (i < n4) ((float4*)dst)[i] = ((const float4*)src)[i];
}

extern "C" void kernel_launch(void* const* d_in, const int* in_sizes, int n_in,
                              void* d_out, int out_size, void* d_ws, size_t ws_size,
                              hipStream_t stream) {
    const float* h      = (const float*)d_in[0];
    const int*   pos    = (const int*)d_in[1];
    const float* wq     = (const float*)d_in[2];
    const float* wk     = (const float*)d_in[3];
    const float* wv     = (const float*)d_in[4];
    const float* wo     = (const float*)d_in[5];
    const float* gate_w = (const float*)d_in[6];
    const float* w1     = (const float*)d_in[7];
    const float* w2     = (const float*)d_in[8];
    const float* w3     = (const float*)d_in[9];
    const float* ln1_w  = (const float*)d_in[10];
    const float* ln2_w  = (const float*)d_in[11];
    float* out = (float*)d_out;

    float* ws = (float*)d_ws;
    const size_t M1 = 1024 * 1024;
    float* xn1 = ws;                 // 2M floats (alias: ob)
    float* ob  = ws;
    float* qb  = ws + 2 * M1;        // 2M (alias: h2)
    float* h2  = ws + 2 * M1;
    float* kb  = ws + 4 * M1;        // 0.5M
    float* vb  = ws + 4 * M1 + M1 / 2; // 0.5M
    float* xn2 = ws + 5 * M1;        // 2M
    __hip_bfloat16* h13b = (__hip_bfloat16*)(ws + 7 * M1);  // ends at 14.34M floats
    float* smallf = ws + 14 * M1 + M1 / 2;
    int*   sel      = (int*)smallf;
    float* wtb      = smallf + 4096;
    int*   counts   = (int*)(smallf + 8192);
    int*   ebase    = (int*)(smallf + 8192 + 16);
    int*   cursor   = (int*)(smallf + 8192 + 32);
    int*   tok_list = (int*)(smallf + 8192 + 64);
    float* wt_list  = smallf + 8192 + 64 + 4352;

    // new-path bf16 staging buffers (beyond 15M floats)
    const size_t WELEM = (size_t)E_ * INTER_ * HID_;       // 29,360,128 bf16 elems per weight
    short* xn2b = (short*)(ws + 15 * M1);                  // T*HID bf16
    short* w1bb = (short*)(ws + 16 * M1);                  // WELEM bf16
    short* w3bb = w1bb + WELEM;                            // WELEM bf16
    short* w2bb = w1bb;                                    // reuse w1b slot after gemm13
    // attention + projection bf16 buffers: alias w1bb region (all consumed BEFORE
    // cvt(w1) runs; single stream => strictly ordered, safe)
    short* qbh  = (short*)(ws + 16 * M1);                  // 2M shorts
    short* kbh  = (short*)(ws + 17 * M1);                  // 0.5M shorts
    short* vbh  = (short*)(ws + 17 * M1 + M1 / 4);         // 0.5M shorts
    short* wqb  = (short*)(ws + 17 * M1 + M1 / 2);         // 1M shorts (1024x1024)
    short* wkb  = (short*)(ws + 18 * M1);                  // 0.25M shorts
    short* wvb  = (short*)(ws + 18 * M1 + M1 / 8);         // 0.25M shorts
    short* wob  = (short*)(ws + 18 * M1 + M1 / 4);         // 1M shorts
    short* xn1b = (short*)(ws + 18 * M1 + 3 * M1 / 4);     // 2M shorts
    short* obh  = (short*)(ws + 19 * M1 + 3 * M1 / 4);     // 2M shorts -> ends 20.75M floats
    const size_t need_bytes = (16 * M1 + WELEM) * sizeof(float);  // ~184.5 MB
    bool big = ws_size >= need_bytes;

    hipLaunchKernelGGL(init_counts_kernel, dim3(1), dim3(64), 0, stream, counts);
    hipLaunchKernelGGL(rmsnorm_kernel, dim3(T_), dim3(256), 0, stream, h, ln1_w, xn1);

    if (big) {
        hipLaunchKernelGGL(cvt_bf16_kernel, dim3(512), dim3(256), 0, stream, wq, wqb, NH_ * HD_ * HID_ / 8);
        hipLaunchKernelGGL(cvt_bf16_kernel, dim3(128), dim3(256), 0, stream, wk, wkb, NKV_ * HD_ * HID_ / 8);
        hipLaunchKernelGGL(cvt_bf16_kernel, dim3(128), dim3(256), 0, stream, wv, wvb, NKV_ * HD_ * HID_ / 8);
        hipLaunchKernelGGL(cvt_bf16_kernel, dim3(512), dim3(256), 0, stream, wo, wob, HID_ * NH_ * HD_ / 8);
        hipLaunchKernelGGL(cvt_bf16_kernel, dim3(1024), dim3(256), 0, stream, xn1, xn1b, T_ * HID_ / 8);
        hipLaunchKernelGGL(gemm_bf16_v2, dim3(NH_ * HD_ / 128, T_ / 128), dim3(256), 0, stream,
                           xn1b, wqb, qb, (const float*)nullptr, T_, NH_ * HD_, HID_);
        hipLaunchKernelGGL(gemm_bf16_v2, dim3(NKV_ * HD_ / 128, T_ / 128), dim3(256), 0, stream,
                           xn1b, wkb, kb, (const float*)nullptr, T_, NKV_ * HD_, HID_);
        hipLaunchKernelGGL(gemm_bf16_v2, dim3(NKV_ * HD_ / 128, T_ / 128), dim3(256), 0, stream,
                           xn1b, wvb, vb, (const float*)nullptr, T_, NKV_ * HD_, HID_);
        {
            int tot = T_ * (NH_ + NKV_) * 32;
            hipLaunchKernelGGL(rope_kernel, dim3((tot + 255) / 256), dim3(256), 0, stream, qb, kb, pos);
        }
        hipLaunchKernelGGL(cvt_bf16_kernel, dim3(1024), dim3(256), 0, stream, qb, qbh, T_ * NH_ * HD_ / 8);
        hipLaunchKernelGGL(cvt_bf16_kernel, dim3(256),  dim3(256), 0, stream, kb, kbh, T_ * NKV_ * HD_ / 8);
        hipLaunchKernelGGL(cvt_bf16_kernel, dim3(256),  dim3(256), 0, stream, vb, vbh, T_ * NKV_ * HD_ / 8);
        hipLaunchKernelGGL(flash_attn_mfma, dim3(32 * 16), dim3(256), 0, stream, qbh, kbh, vbh, obh);
        hipLaunchKernelGGL(gemm_bf16_v2, dim3(HID_ / 128, T_ / 128), dim3(256), 0, stream,
                           obh, wob, h2, h, T_, HID_, NH_ * HD_);
    } else {
        hipLaunchKernelGGL(gemm_f32, dim3(16, 32), dim3(256), 0, stream, xn1, wq, qb, (const float*)nullptr, T_, NH_ * HD_, HID_);
        hipLaunchKernelGGL(gemm_f32, dim3(4, 32),  dim3(256), 0, stream, xn1, wk, kb, (const float*)nullptr, T_, NKV_ * HD_, HID_);
        hipLaunchKernelGGL(gemm_f32, dim3(4, 32),  dim3(256), 0, stream, xn1, wv, vb, (const float*)nullptr, T_, NKV_ * HD_, HID_);
        {
            int tot = T_ * (NH_ + NKV_) * 32;
            hipLaunchKernelGGL(rope_kernel, dim3((tot + 255) / 256), dim3(256), 0, stream, qb, kb, pos);
        }
        hipLaunchKernelGGL(flash_attn_kernel, dim3(32 * 16), dim3(256), 0, stream, qb, kb, vb, ob);
        hipLaunchKernelGGL(gemm_f32, dim3(16, 32), dim3(256), 0, stream, ob, wo, h2, h, T_, HID_, NH_ * HD_);
    }

    hipLaunchKernelGGL(rmsnorm_kernel, dim3(T_), dim3(256), 0, stream, h2, ln2_w, xn2);
    hipLaunchKernelGGL(gating_kernel, dim3(T_), dim3(64), 0, stream, xn2, gate_w, sel, wtb, counts);
    hipLaunchKernelGGL(prefix_kernel, dim3(1), dim3(64), 0, stream, counts, ebase, cursor);
    hipLaunchKernelGGL(scatter_kernel, dim3((T_ + 255) / 256), dim3(256), 0, stream, sel, wtb, cursor, tok_list, wt_list);

    if (big) {
        const int n8w = (int)(WELEM / 8);
        hipLaunchKernelGGL(cvt_bf16_kernel, dim3(2048), dim3(256), 0, stream, w1, w1bb, n8w);
        hipLaunchKernelGGL(cvt_bf16_kernel, dim3(2048), dim3(256), 0, stream, w3, w3bb, n8w);
        hipLaunchKernelGGL(cvt_bf16_kernel, dim3(256),  dim3(256), 0, stream, xn2, xn2b, T_ * HID_ / 8);
        // 256Mx128N tiles: grid y=8 covers cnt<=2048
        hipLaunchKernelGGL(moe_gemm13_v3, dim3(INTER_ / 128, 8, E_), dim3(512), 0, stream,
                           xn2b, w1bb, w3bb, tok_list, ebase, counts, h13b);
        hipLaunchKernelGGL(cvt_bf16_kernel, dim3(2048), dim3(256), 0, stream, w2, w2bb, n8w);
        hipLaunchKernelGGL(copy4_kernel, dim3((T_ * HID_ / 4 + 255) / 256), dim3(256), 0, stream, h2, out, T_ * HID_ / 4);
        // 256x256 tiles, split-K=2: z = e*2 + ks
        hipLaunchKernelGGL(moe_gemm2_v3, dim3(HID_ / 256, 8, E_ * 2), dim3(512), 0, stream,
                           (const short*)h13b, w2bb, tok_list, wt_list, ebase, counts, out);
    } else {
        hipLaunchKernelGGL(moe_gemm13_mfma, dim3(INTER_ / 128, 16, E_), dim3(256), 0, stream,
                           xn2, w1, w3, tok_list, ebase, counts, h13b);
        hipLaunchKernelGGL(copy4_kernel, dim3((T_ * HID_ / 4 + 255) / 256), dim3(256), 0, stream, h2, out, T_ * HID_ / 4);
        hipLaunchKernelGGL(moe_gemm2_mfma, dim3(HID_ / 128, 16, E_), dim3(256), 0, stream,
                           h13b, w2, tok_list, wt_list, ebase, counts, out);
    }
}

// Round 6
// 814.015 us; speedup vs baseline: 1.1413x; 1.1413x over previous
//
#include <hip/hip_runtime.h>
#include <hip/hip_bf16.h>
#include <math.h>

#define T_    2048
#define HID_  1024
#define NH_   16
#define NKV_  4
#define HD_   64
#define E_    8
#define TOPK_ 2
#define INTER_ 3584
#define EPS_  1e-6f

typedef __attribute__((ext_vector_type(8))) short short8;
typedef __attribute__((ext_vector_type(4))) short short4v;
typedef __attribute__((ext_vector_type(4))) float floatx4;

__device__ inline short f2bf(float f) {
    __hip_bfloat16 b = __float2bfloat16(f);
    return *reinterpret_cast<short*>(&b);
}

__device__ inline float bf2f(short s) {
    __hip_bfloat16 b = *reinterpret_cast<__hip_bfloat16*>(&s);
    return __bfloat162float(b);
}

__device__ inline void cvt_store16(short* dst, float4 a, float4 b, float4 c, float4 d) {
    short8 lo, hi;
    lo[0] = f2bf(a.x); lo[1] = f2bf(a.y); lo[2] = f2bf(a.z); lo[3] = f2bf(a.w);
    lo[4] = f2bf(b.x); lo[5] = f2bf(b.y); lo[6] = f2bf(b.z); lo[7] = f2bf(b.w);
    hi[0] = f2bf(c.x); hi[1] = f2bf(c.y); hi[2] = f2bf(c.z); hi[3] = f2bf(c.w);
    hi[4] = f2bf(d.x); hi[5] = f2bf(d.y); hi[6] = f2bf(d.z); hi[7] = f2bf(d.w);
    *(short8*)dst = lo;
    *(short8*)(dst + 8) = hi;
}

// async global->LDS, 16B per lane. LDS dest must be wave-uniform-base + lane*16.
__device__ inline void async_copy16(short* lds, const short* g) {
    __builtin_amdgcn_global_load_lds((const __attribute__((address_space(1))) void*)g,
                                     (__attribute__((address_space(3))) void*)lds, 16, 0, 0);
}

// ---------------- RMSNorm: one block (256 thr) per row ----------------
__global__ __launch_bounds__(256) void rmsnorm_kernel(const float* __restrict__ x,
                                                      const float* __restrict__ w,
                                                      float* __restrict__ o) {
    int t = blockIdx.x;
    const float* xr = x + (size_t)t * HID_;
    float s = 0.f;
    for (int d = threadIdx.x; d < HID_; d += 256) { float v = xr[d]; s += v * v; }
    __shared__ float red[256];
    red[threadIdx.x] = s; __syncthreads();
    for (int off = 128; off > 0; off >>= 1) {
        if (threadIdx.x < off) red[threadIdx.x] += red[threadIdx.x + off];
        __syncthreads();
    }
    float inv = rsqrtf(red[0] / (float)HID_ + EPS_);
    for (int d = threadIdx.x; d < HID_; d += 256)
        o[(size_t)t * HID_ + d] = w[d] * xr[d] * inv;
}

// ---------------- Generic fp32 GEMM (fallback path only) ----------------
__global__ __launch_bounds__(256) void gemm_f32(const float* __restrict__ A,
                                                const float* __restrict__ B,
                                                float* __restrict__ C,
                                                const float* __restrict__ addsrc,
                                                int M, int N, int K) {
    __shared__ float As[16][65];
    __shared__ float Bs[16][65];
    int tid = threadIdx.x;
    int tx = tid & 15, ty = tid >> 4;
    int bm = blockIdx.y * 64, bn = blockIdx.x * 64;
    float acc[4][4];
#pragma unroll
    for (int i = 0; i < 4; i++)
#pragma unroll
        for (int j = 0; j < 4; j++) acc[i][j] = 0.f;

    int mL[4], kL[4];
#pragma unroll
    for (int l = 0; l < 4; l++) { int idx = tid + l * 256; mL[l] = idx >> 4; kL[l] = idx & 15; }

    for (int k0 = 0; k0 < K; k0 += 16) {
#pragma unroll
        for (int l = 0; l < 4; l++) {
            int m = mL[l], kk = kL[l];
            int gr = bm + m;
            As[kk][m] = (gr < M) ? A[(size_t)gr * K + k0 + kk] : 0.f;
            int gc = bn + m;
            Bs[kk][m] = (gc < N) ? B[(size_t)gc * K + k0 + kk] : 0.f;
        }
        __syncthreads();
#pragma unroll
        for (int kk = 0; kk < 16; kk++) {
            float a[4], b[4];
#pragma unroll
            for (int i = 0; i < 4; i++) a[i] = As[kk][ty * 4 + i];
#pragma unroll
            for (int j = 0; j < 4; j++) b[j] = Bs[kk][tx * 4 + j];
#pragma unroll
            for (int i = 0; i < 4; i++)
#pragma unroll
                for (int j = 0; j < 4; j++) acc[i][j] += a[i] * b[j];
        }
        __syncthreads();
    }
#pragma unroll
    for (int i = 0; i < 4; i++) {
        int r = bm + ty * 4 + i;
        if (r >= M) continue;
#pragma unroll
        for (int j = 0; j < 4; j++) {
            int c = bn + tx * 4 + j;
            if (c >= N) continue;
            float v = acc[i][j];
            if (addsrc) v += addsrc[(size_t)r * N + c];
            C[(size_t)r * N + c] = v;
        }
    }
}

// ---------------- bf16 MFMA GEMM: C[M,N] = A[M,K] @ B[N,K]^T (+addsrc), fp32 out ----------------
__global__ __launch_bounds__(256, 2) void gemm_bf16_v2(const short* __restrict__ A,
                                                       const short* __restrict__ B,
                                                       float* __restrict__ C,
                                                       const float* __restrict__ addsrc,
                                                       int M, int N, int K) {
    int bm = blockIdx.y * 128;
    int bn = blockIdx.x * 128;

    __shared__ alignas(16) short lds[2][2][128 * 32];  // 32 KiB

    int tid = threadIdx.x;
    int sr = tid >> 2;
    int sc = (tid & 3) * 8;
    int ldst = tid * 8;

    const short* aG0 = A + (size_t)(bm + sr) * K + sc;
    const short* aG1 = aG0 + (size_t)64 * K;
    const short* bG0 = B + (size_t)(bn + sr) * K + sc;
    const short* bG1 = bG0 + (size_t)64 * K;

    int wvid = tid >> 6, lane = tid & 63;
    int wm = (wvid >> 1) * 64, wn = (wvid & 1) * 64;
    int l15 = lane & 15, quad = lane >> 4;

    floatx4 acc[4][4];
#pragma unroll
    for (int i = 0; i < 4; i++)
#pragma unroll
        for (int j = 0; j < 4; j++) acc[i][j] = (floatx4)0.f;

#define STAGEG(b, k0) do {                                          \
        async_copy16(&lds[b][0][ldst],        aG0 + (k0));          \
        async_copy16(&lds[b][0][ldst + 2048], aG1 + (k0));          \
        async_copy16(&lds[b][1][ldst],        bG0 + (k0));          \
        async_copy16(&lds[b][1][ldst + 2048], bG1 + (k0));          \
    } while (0)

    STAGEG(0, 0);
    __syncthreads();

    int cur = 0;
    for (int k0 = 0; k0 < K; k0 += 32) {
        if (k0 + 32 < K) STAGEG(cur ^ 1, k0 + 32);

        const short* XaR = &lds[cur][0][(wm + l15) * 32 + quad * 8];
        const short* WsR = &lds[cur][1][(wn + l15) * 32 + quad * 8];
        short8 af[4], bf_[4];
#pragma unroll
        for (int i = 0; i < 4; i++) af[i] = *(const short8*)(XaR + i * 16 * 32);
#pragma unroll
        for (int j = 0; j < 4; j++) bf_[j] = *(const short8*)(WsR + j * 16 * 32);
#pragma unroll
        for (int i = 0; i < 4; i++)
#pragma unroll
            for (int j = 0; j < 4; j++)
                acc[i][j] = __builtin_amdgcn_mfma_f32_16x16x32_bf16(af[i], bf_[j], acc[i][j], 0, 0, 0);
        __syncthreads();
        cur ^= 1;
    }
#undef STAGEG

#pragma unroll
    for (int i = 0; i < 4; i++) {
#pragma unroll
        for (int reg = 0; reg < 4; reg++) {
            int r = bm + wm + i * 16 + quad * 4 + reg;
            size_t rowoff = (size_t)r * N;
#pragma unroll
            for (int j = 0; j < 4; j++) {
                int c = bn + wn + j * 16 + l15;
                float v = acc[i][j][reg];
                if (addsrc) v += addsrc[rowoff + c];
                C[rowoff + c] = v;
            }
        }
    }
}

// ---------------- RoPE in-place on q and k ----------------
__global__ void rope_kernel(float* __restrict__ qb, float* __restrict__ kb,
                            const int* __restrict__ pos_ids) {
    int idx = blockIdx.x * blockDim.x + threadIdx.x;
    const int totq = T_ * NH_ * 32;
    const int totk = T_ * NKV_ * 32;
    if (idx >= totq + totk) return;
    float* buf; int t, hh, i, hw;
    if (idx < totq) { buf = qb; hw = NH_;  t = idx / (NH_ * 32); int r = idx % (NH_ * 32); hh = r / 32; i = r % 32; }
    else { idx -= totq; buf = kb; hw = NKV_; t = idx / (NKV_ * 32); int r = idx % (NKV_ * 32); hh = r / 32; i = r % 32; }
    float pos = (float)pos_ids[t];
    float inv = expf(-(float)i * (13.815510558f / 32.0f));
    float fr = pos * inv;
    float c = cosf(fr), s = sinf(fr);
    size_t base = (size_t)t * hw * 64 + (size_t)hh * 64;
    float x1 = buf[base + i], x2 = buf[base + i + 32];
    buf[base + i]      = x1 * c - x2 * s;
    buf[base + i + 32] = x2 * c + x1 * s;
}

// ---------------- Flash attention v2: bf16 MFMA, bf16 output ----------------
__global__ __launch_bounds__(256) void flash_attn_mfma(const short* __restrict__ qbh,
                                                       const short* __restrict__ kbh,
                                                       const short* __restrict__ vbh,
                                                       short* __restrict__ obh) {
    __shared__ alignas(16) short Ks[64][80];
    __shared__ alignas(16) short Vt[64][80];
    __shared__ alignas(16) short Ps[64][80];

    int bid = blockIdx.x;
    int h = bid & 15;
    int qr = bid >> 4;
    int qt = (qr & 1) ? (31 - (qr >> 1)) : (qr >> 1);
    int q0 = qt * 64;
    int kvh = h >> 2;
    int tid = threadIdx.x;
    int w = tid >> 6, lane = tid & 63;
    int l15 = lane & 15, quad = lane >> 4;
    int str = tid >> 2, stc = tid & 3;

    short8 aq0, aq1;
    {
        const short* qrow = qbh + (size_t)(q0 + 16 * w + l15) * (NH_ * HD_) + h * HD_ + quad * 8;
        aq0 = *(const short8*)(qrow);
        aq1 = *(const short8*)(qrow + 32);
    }

    floatx4 o_acc[4];
    float m_i[4], l_i[4];
#pragma unroll
    for (int j = 0; j < 4; j++) o_acc[j] = (floatx4)0.f;
#pragma unroll
    for (int r = 0; r < 4; r++) { m_i[r] = -INFINITY; l_i[r] = 0.f; }

    int nt = q0 / 64 + 1;

    const short* kg = kbh + (size_t)str * (NKV_ * HD_) + kvh * HD_ + stc * 8;
    const short* vg = vbh + (size_t)str * (NKV_ * HD_) + kvh * HD_ + stc * 8;
    short8 kr0 = *(const short8*)kg;
    short8 kr1 = *(const short8*)(kg + 32);
    short8 vr0 = *(const short8*)vg;
    short8 vr1 = *(const short8*)(vg + 32);

    for (int it = 0; it < nt; ++it) {
        int t0 = it * 64;
        __syncthreads();
        *(short8*)&Ks[str][stc * 8]      = kr0;
        *(short8*)&Ks[str][32 + stc * 8] = kr1;
#pragma unroll
        for (int i = 0; i < 8; i++) {
            Vt[stc * 8 + i][str]      = vr0[i];
            Vt[32 + stc * 8 + i][str] = vr1[i];
        }
        if (it + 1 < nt) {
            const short* kgn = kbh + (size_t)(t0 + 64 + str) * (NKV_ * HD_) + kvh * HD_ + stc * 8;
            const short* vgn = vbh + (size_t)(t0 + 64 + str) * (NKV_ * HD_) + kvh * HD_ + stc * 8;
            kr0 = *(const short8*)kgn;
            kr1 = *(const short8*)(kgn + 32);
            vr0 = *(const short8*)vgn;
            vr1 = *(const short8*)(vgn + 32);
        }
        __syncthreads();

        floatx4 s[4];
#pragma unroll
        for (int j = 0; j < 4; j++) s[j] = (floatx4)0.f;
        __builtin_amdgcn_s_setprio(1);
#pragma unroll
        for (int j = 0; j < 4; j++) {
            short8 bk0 = *(const short8*)&Ks[16 * j + l15][quad * 8];
            short8 bk1 = *(const short8*)&Ks[16 * j + l15][32 + quad * 8];
            s[j] = __builtin_amdgcn_mfma_f32_16x16x32_bf16(aq0, bk0, s[j], 0, 0, 0);
            s[j] = __builtin_amdgcn_mfma_f32_16x16x32_bf16(aq1, bk1, s[j], 0, 0, 0);
        }
        __builtin_amdgcn_s_setprio(0);

        bool diag = (t0 == q0);
#pragma unroll
        for (int j = 0; j < 4; j++)
#pragma unroll
            for (int reg = 0; reg < 4; reg++) {
                s[j][reg] *= 0.125f;
                if (diag && (16 * j + l15 > 16 * w + quad * 4 + reg)) s[j][reg] = -INFINITY;
            }

#pragma unroll
        for (int reg = 0; reg < 4; reg++) {
            float mx = fmaxf(fmaxf(s[0][reg], s[1][reg]), fmaxf(s[2][reg], s[3][reg]));
#pragma unroll
            for (int off = 8; off >= 1; off >>= 1) mx = fmaxf(mx, __shfl_xor(mx, off));
            float mn = fmaxf(m_i[reg], mx);
            float alpha = __expf(m_i[reg] - mn);
            float rs = 0.f;
#pragma unroll
            for (int j = 0; j < 4; j++) { float p = __expf(s[j][reg] - mn); s[j][reg] = p; rs += p; }
#pragma unroll
            for (int off = 8; off >= 1; off >>= 1) rs += __shfl_xor(rs, off);
            l_i[reg] = l_i[reg] * alpha + rs;
            m_i[reg] = mn;
#pragma unroll
            for (int j = 0; j < 4; j++) o_acc[j][reg] *= alpha;
        }

#pragma unroll
        for (int j = 0; j < 4; j++)
#pragma unroll
            for (int reg = 0; reg < 4; reg++)
                Ps[16 * w + quad * 4 + reg][16 * j + l15] = f2bf(s[j][reg]);
        __asm__ volatile("s_waitcnt lgkmcnt(0)" ::: "memory");

        short8 ap0 = *(const short8*)&Ps[16 * w + l15][quad * 8];
        short8 ap1 = *(const short8*)&Ps[16 * w + l15][32 + quad * 8];
        __builtin_amdgcn_s_setprio(1);
#pragma unroll
        for (int j = 0; j < 4; j++) {
            short8 bv0 = *(const short8*)&Vt[16 * j + l15][quad * 8];
            short8 bv1 = *(const short8*)&Vt[16 * j + l15][32 + quad * 8];
            o_acc[j] = __builtin_amdgcn_mfma_f32_16x16x32_bf16(ap0, bv0, o_acc[j], 0, 0, 0);
            o_acc[j] = __builtin_amdgcn_mfma_f32_16x16x32_bf16(ap1, bv1, o_acc[j], 0, 0, 0);
        }
        __builtin_amdgcn_s_setprio(0);
    }

#pragma unroll
    for (int reg = 0; reg < 4; reg++) {
        float invl = 1.f / l_i[reg];
        size_t rbase = (size_t)(q0 + 16 * w + quad * 4 + reg) * (NH_ * HD_) + h * HD_;
#pragma unroll
        for (int j = 0; j < 4; j++)
            obh[rbase + 16 * j + l15] = f2bf(o_acc[j][reg] * invl);
    }
}

// ---------------- Flash attention (fp32 fallback) ----------------
__global__ __launch_bounds__(256) void flash_attn_kernel(const float* __restrict__ qb,
                                                         const float* __restrict__ kb,
                                                         const float* __restrict__ vb,
                                                         float* __restrict__ ob) {
    __shared__ float Qs[64][68];
    __shared__ float Ks[64][68];
    __shared__ float Vs[64][68];
    __shared__ float Ps[64][68];

    int bid = blockIdx.x;
    int h = bid & 15;
    int qr = bid >> 4;
    int qt = (qr & 1) ? (31 - (qr >> 1)) : (qr >> 1);
    int q0 = qt * 64;
    int kvh = h >> 2;
    int tid = threadIdx.x;
    int tx = tid & 15, ty = tid >> 4;

#pragma unroll
    for (int l = 0; l < 16; l++) {
        int idx = l * 256 + tid;
        int m = idx >> 6, d = idx & 63;
        Qs[d][m] = qb[(size_t)(q0 + m) * (NH_ * HD_) + h * HD_ + d];
    }

    float o_acc[4][4];
    float m_i[4], l_i[4];
#pragma unroll
    for (int i = 0; i < 4; i++) {
        m_i[i] = -INFINITY; l_i[i] = 0.f;
#pragma unroll
        for (int j = 0; j < 4; j++) o_acc[i][j] = 0.f;
    }

    for (int t0 = 0; t0 <= q0; t0 += 64) {
        __syncthreads();
#pragma unroll
        for (int l = 0; l < 16; l++) {
            int idx = l * 256 + tid;
            int m = idx >> 6, d = idx & 63;
            size_t g = (size_t)(t0 + m) * (NKV_ * HD_) + kvh * HD_ + d;
            Ks[d][m] = kb[g];
            Vs[m][d] = vb[g];
        }
        __syncthreads();

        float s[4][4];
#pragma unroll
        for (int i = 0; i < 4; i++)
#pragma unroll
            for (int j = 0; j < 4; j++) s[i][j] = 0.f;
#pragma unroll 4
        for (int kk = 0; kk < 64; kk++) {
            float4 a4 = *(const float4*)&Qs[kk][ty * 4];
            float4 b4 = *(const float4*)&Ks[kk][tx * 4];
            float a[4] = {a4.x, a4.y, a4.z, a4.w};
            float b[4] = {b4.x, b4.y, b4.z, b4.w};
#pragma unroll
            for (int i = 0; i < 4; i++)
#pragma unroll
                for (int j = 0; j < 4; j++) s[i][j] += a[i] * b[j];
        }

        bool diag = (t0 == q0);
#pragma unroll
        for (int i = 0; i < 4; i++) {
#pragma unroll
            for (int j = 0; j < 4; j++) {
                s[i][j] *= 0.125f;
                if (diag && (t0 + tx * 4 + j > q0 + ty * 4 + i)) s[i][j] = -INFINITY;
            }
        }

#pragma unroll
        for (int i = 0; i < 4; i++) {
            float mx = fmaxf(fmaxf(s[i][0], s[i][1]), fmaxf(s[i][2], s[i][3]));
#pragma unroll
            for (int off = 8; off >= 1; off >>= 1) mx = fmaxf(mx, __shfl_xor(mx, off));
            float mn = fmaxf(m_i[i], mx);
            float alpha = __expf(m_i[i] - mn);
            float rs = 0.f;
#pragma unroll
            for (int j = 0; j < 4; j++) { float p = __expf(s[i][j] - mn); s[i][j] = p; rs += p; }
#pragma unroll
            for (int off = 8; off >= 1; off >>= 1) rs += __shfl_xor(rs, off);
            l_i[i] = l_i[i] * alpha + rs;
            m_i[i] = mn;
#pragma unroll
            for (int j = 0; j < 4; j++) o_acc[i][j] *= alpha;
        }

#pragma unroll
        for (int j = 0; j < 4; j++)
#pragma unroll
            for (int i = 0; i < 4; i++)
                Ps[tx * 4 + j][ty * 4 + i] = s[i][j];
        __syncthreads();

#pragma unroll 4
        for (int kk = 0; kk < 64; kk++) {
            float4 a4 = *(const float4*)&Ps[kk][ty * 4];
            float4 b4 = *(const float4*)&Vs[kk][tx * 4];
            float a[4] = {a4.x, a4.y, a4.z, a4.w};
            float b[4] = {b4.x, b4.y, b4.z, b4.w};
#pragma unroll
            for (int i = 0; i < 4; i++)
#pragma unroll
                for (int j = 0; j < 4; j++) o_acc[i][j] += a[i] * b[j];
        }
    }

#pragma unroll
    for (int i = 0; i < 4; i++) {
        float invl = 1.f / l_i[i];
        int r = q0 + ty * 4 + i;
#pragma unroll
        for (int j = 0; j < 4; j++)
            ob[(size_t)r * (NH_ * HD_) + h * HD_ + tx * 4 + j] = o_acc[i][j] * invl;
    }
}

// ---------------- Gating: one wave per token ----------------
__global__ __launch_bounds__(64) void gating_kernel(const float* __restrict__ xn2,
                                                    const float* __restrict__ gate_w,
                                                    int* __restrict__ sel,
                                                    float* __restrict__ wt,
                                                    int* __restrict__ counts) {
    int t = blockIdx.x, lane = threadIdx.x;
    const float* x = xn2 + (size_t)t * HID_;
    float logits[E_];
    for (int e = 0; e < E_; e++) {
        float p = 0.f;
        for (int d = lane; d < HID_; d += 64) p += x[d] * gate_w[(size_t)e * HID_ + d];
#pragma unroll
        for (int off = 32; off > 0; off >>= 1) p += __shfl_xor(p, off);
        logits[e] = p;
    }
    float mx = logits[0];
    for (int e = 1; e < E_; e++) mx = fmaxf(mx, logits[e]);
    float pr[E_]; float sum = 0.f;
    for (int e = 0; e < E_; e++) { pr[e] = __expf(logits[e] - mx); sum += pr[e]; }
    int e1 = 0; float p1 = pr[0];
    for (int e = 1; e < E_; e++) if (pr[e] > p1) { p1 = pr[e]; e1 = e; }
    int e2 = -1; float p2 = -1.f;
    for (int e = 0; e < E_; e++) if (e != e1 && pr[e] > p2) { p2 = pr[e]; e2 = e; }
    if (lane == 0) {
        float denom = p1 + p2;
        sel[t * 2] = e1; sel[t * 2 + 1] = e2;
        wt[t * 2] = p1 / denom; wt[t * 2 + 1] = p2 / denom;
        atomicAdd(&counts[e1], 1);
        atomicAdd(&counts[e2], 1);
    }
}

__global__ void init_counts_kernel(int* counts) {
    if (threadIdx.x < E_) counts[threadIdx.x] = 0;
}

__global__ void prefix_kernel(const int* __restrict__ counts, int* __restrict__ ebase,
                              int* __restrict__ cursor) {
    if (threadIdx.x == 0) {
        int b = 0;
        for (int e = 0; e < E_; e++) { ebase[e] = b; cursor[e] = b; b += counts[e]; }
    }
}

// scatter: also records each (token, choice) -> slot index for the combine pass
__global__ void scatter_kernel(const int* __restrict__ sel, const float* __restrict__ wt,
                               int* __restrict__ cursor, int* __restrict__ tok_list,
                               float* __restrict__ wt_list, int* __restrict__ slot_list) {
    int t = blockIdx.x * blockDim.x + threadIdx.x;
    if (t >= T_) return;
    for (int j = 0; j < 2; j++) {
        int e = sel[t * 2 + j];
        float w = wt[t * 2 + j];
        int p = atomicAdd(&cursor[e], 1);
        tok_list[p] = t;
        wt_list[p] = w;
        slot_list[t * 2 + j] = p;
    }
}

// ---------------- fp32 -> bf16 bulk convert (RNE, memory-bound) ----------------
__global__ __launch_bounds__(256) void cvt_bf16_kernel(const float* __restrict__ src,
                                                       short* __restrict__ dst, int n8) {
    int stride = gridDim.x * blockDim.x;
    for (int i = blockIdx.x * blockDim.x + threadIdx.x; i < n8; i += stride) {
        float4 a = ((const float4*)src)[2 * i];
        float4 b = ((const float4*)src)[2 * i + 1];
        short8 o;
        o[0] = f2bf(a.x); o[1] = f2bf(a.y); o[2] = f2bf(a.z); o[3] = f2bf(a.w);
        o[4] = f2bf(b.x); o[5] = f2bf(b.y); o[6] = f2bf(b.z); o[7] = f2bf(b.w);
        ((short8*)dst)[i] = o;
    }
}

// ---------------- MoE GEMM 1&3 v2 (reverted proven version) ----------------
__global__ __launch_bounds__(256, 2) void moe_gemm13_v2(const short* __restrict__ Xb,
                                                        const short* __restrict__ w1b,
                                                        const short* __restrict__ w3b,
                                                        const int* __restrict__ tok_list,
                                                        const int* __restrict__ ebase,
                                                        const int* __restrict__ counts,
                                                        __hip_bfloat16* __restrict__ h13b) {
    int e = blockIdx.z;
    int cnt = counts[e];
    int bm = blockIdx.y * 128;
    if (cnt <= 0 || bm >= cnt) return;
    int base = ebase[e];
    int bn = blockIdx.x * 128;

    __shared__ alignas(16) short lds[2][3][128 * 32];  // 48 KiB

    int tid = threadIdx.x;
    int sr = tid >> 2;
    int sc = (tid & 3) * 8;
    int ldst = tid * 8;

    int lr0 = bm + sr, lr1 = bm + sr + 64;
    int tok0 = tok_list[base + (lr0 < cnt ? lr0 : cnt - 1)];
    int tok1 = tok_list[base + (lr1 < cnt ? lr1 : cnt - 1)];
    const short* aG0 = Xb + (size_t)tok0 * HID_ + sc;
    const short* aG1 = Xb + (size_t)tok1 * HID_ + sc;
    const short* b1G0 = w1b + (size_t)e * INTER_ * HID_ + (size_t)(bn + sr) * HID_ + sc;
    const short* b1G1 = b1G0 + (size_t)64 * HID_;
    const short* b3G0 = w3b + (size_t)e * INTER_ * HID_ + (size_t)(bn + sr) * HID_ + sc;
    const short* b3G1 = b3G0 + (size_t)64 * HID_;

    int wvid = tid >> 6, lane = tid & 63;
    int wm = (wvid >> 1) * 64, wn = (wvid & 1) * 64;
    int l15 = lane & 15, quad = lane >> 4;

    floatx4 acc1[4][4], acc3[4][4];
#pragma unroll
    for (int i = 0; i < 4; i++)
#pragma unroll
        for (int j = 0; j < 4; j++) { acc1[i][j] = (floatx4)0.f; acc3[i][j] = (floatx4)0.f; }

#define STAGE13(b, k0) do {                                          \
        async_copy16(&lds[b][0][ldst],        aG0 + (k0));           \
        async_copy16(&lds[b][0][ldst + 2048], aG1 + (k0));           \
        async_copy16(&lds[b][1][ldst],        b1G0 + (k0));          \
        async_copy16(&lds[b][1][ldst + 2048], b1G1 + (k0));          \
        async_copy16(&lds[b][2][ldst],        b3G0 + (k0));          \
        async_copy16(&lds[b][2][ldst + 2048], b3G1 + (k0));          \
    } while (0)

    STAGE13(0, 0);
    __syncthreads();

    int cur = 0;
    for (int k0 = 0; k0 < HID_; k0 += 32) {
        if (k0 + 32 < HID_) STAGE13(cur ^ 1, k0 + 32);

        const short* XaR = &lds[cur][0][(wm + l15) * 32 + quad * 8];
        const short* W1r = &lds[cur][1][(wn + l15) * 32 + quad * 8];
        const short* W3r = &lds[cur][2][(wn + l15) * 32 + quad * 8];
        short8 af[4], b1f[4], b3f[4];
#pragma unroll
        for (int i = 0; i < 4; i++) af[i] = *(const short8*)(XaR + i * 16 * 32);
#pragma unroll
        for (int j = 0; j < 4; j++) {
            b1f[j] = *(const short8*)(W1r + j * 16 * 32);
            b3f[j] = *(const short8*)(W3r + j * 16 * 32);
        }
#pragma unroll
        for (int i = 0; i < 4; i++)
#pragma unroll
            for (int j = 0; j < 4; j++) {
                acc1[i][j] = __builtin_amdgcn_mfma_f32_16x16x32_bf16(af[i], b1f[j], acc1[i][j], 0, 0, 0);
                acc3[i][j] = __builtin_amdgcn_mfma_f32_16x16x32_bf16(af[i], b3f[j], acc3[i][j], 0, 0, 0);
            }
        __syncthreads();
        cur ^= 1;
    }
#undef STAGE13

#pragma unroll
    for (int i = 0; i < 4; i++) {
#pragma unroll
        for (int reg = 0; reg < 4; reg++) {
            int lrow = bm + wm + i * 16 + quad * 4 + reg;
            if (lrow >= cnt) continue;
            size_t rowoff = (size_t)(base + lrow) * INTER_;
#pragma unroll
            for (int j = 0; j < 4; j++) {
                float a = acc1[i][j][reg];
                float v = (a / (1.f + __expf(-a))) * acc3[i][j][reg];
                h13b[rowoff + bn + wn + j * 16 + l15] = __float2bfloat16(v);
            }
        }
    }
}

// ---------------- MoE GEMM 2 v4: 128x128 tile, split-K=4, NO atomics ----------------
// Partial sums stored bf16 to pout[k][slot][HID_] (plain stores). blockIdx.z = e*4+ks.
// 4x more blocks than v2 (4+ blocks/CU) and zero atomic round-trips in the epilogue.
__global__ __launch_bounds__(256, 2) void moe_gemm2_v4(const short* __restrict__ h13s,
                                                       const short* __restrict__ w2b,
                                                       const int* __restrict__ ebase,
                                                       const int* __restrict__ counts,
                                                       short* __restrict__ pout) {
    int zz = blockIdx.z;
    int e = zz >> 2, ks = zz & 3;
    int cnt = counts[e];
    int bm = blockIdx.y * 128;
    if (cnt <= 0 || bm >= cnt) return;
    int base = ebase[e];
    int bn = blockIdx.x * 128;
    const int KS = INTER_ / 4;            // 896
    const int K0 = ks * KS;

    __shared__ alignas(16) short lds[2][2][128 * 32];  // 32 KiB

    int tid = threadIdx.x;
    int sr = tid >> 2;
    int sc = (tid & 3) * 8;
    int ldst = tid * 8;

    int lr0 = bm + sr, lr1 = bm + sr + 64;
    int slot0 = base + (lr0 < cnt ? lr0 : cnt - 1);
    int slot1 = base + (lr1 < cnt ? lr1 : cnt - 1);
    const short* aG0 = h13s + (size_t)slot0 * INTER_ + K0 + sc;
    const short* aG1 = h13s + (size_t)slot1 * INTER_ + K0 + sc;
    const short* bG0 = w2b + (size_t)e * HID_ * INTER_ + (size_t)(bn + sr) * INTER_ + K0 + sc;
    const short* bG1 = bG0 + (size_t)64 * INTER_;

    int wvid = tid >> 6, lane = tid & 63;
    int wm = (wvid >> 1) * 64, wn = (wvid & 1) * 64;
    int l15 = lane & 15, quad = lane >> 4;

    floatx4 acc[4][4];
#pragma unroll
    for (int i = 0; i < 4; i++)
#pragma unroll
        for (int j = 0; j < 4; j++) acc[i][j] = (floatx4)0.f;

#define STAGE2(b, k0) do {                                          \
        async_copy16(&lds[b][0][ldst],        aG0 + (k0));          \
        async_copy16(&lds[b][0][ldst + 2048], aG1 + (k0));          \
        async_copy16(&lds[b][1][ldst],        bG0 + (k0));          \
        async_copy16(&lds[b][1][ldst + 2048], bG1 + (k0));          \
    } while (0)

    STAGE2(0, 0);
    __syncthreads();

    int cur = 0;
    for (int k0 = 0; k0 < KS; k0 += 32) {
        if (k0 + 32 < KS) STAGE2(cur ^ 1, k0 + 32);

        const short* XaR = &lds[cur][0][(wm + l15) * 32 + quad * 8];
        const short* WsR = &lds[cur][1][(wn + l15) * 32 + quad * 8];
        short8 af[4], bf_[4];
#pragma unroll
        for (int i = 0; i < 4; i++) af[i] = *(const short8*)(XaR + i * 16 * 32);
#pragma unroll
        for (int j = 0; j < 4; j++) bf_[j] = *(const short8*)(WsR + j * 16 * 32);
#pragma unroll
        for (int i = 0; i < 4; i++)
#pragma unroll
            for (int j = 0; j < 4; j++)
                acc[i][j] = __builtin_amdgcn_mfma_f32_16x16x32_bf16(af[i], bf_[j], acc[i][j], 0, 0, 0);
        __syncthreads();
        cur ^= 1;
    }
#undef STAGE2

    // plain bf16 stores of partials: pout[ks][slot][col]
#pragma unroll
    for (int i = 0; i < 4; i++) {
#pragma unroll
        for (int reg = 0; reg < 4; reg++) {
            int lrow = bm + wm + i * 16 + quad * 4 + reg;
            if (lrow >= cnt) continue;
            short* prow = pout + ((size_t)ks * (2 * T_) + (base + lrow)) * HID_ + bn + wn;
#pragma unroll
            for (int j = 0; j < 4; j++)
                prow[j * 16 + l15] = f2bf(acc[i][j][reg]);
        }
    }
}

// ---------------- MoE combine: out[t] = h2[t] + sum_j wt_j * sum_k pout[k][slot_j] ----------------
__global__ __launch_bounds__(256) void moe_combine_kernel(const float* __restrict__ h2,
                                                          const short* __restrict__ pout,
                                                          const int* __restrict__ slot_list,
                                                          const float* __restrict__ wtb,
                                                          float* __restrict__ out) {
    int t = blockIdx.x;
    int d = threadIdx.x * 4;
    float4 r = *(const float4*)(h2 + (size_t)t * HID_ + d);
    int s0 = slot_list[t * 2], s1 = slot_list[t * 2 + 1];
    float w0 = wtb[t * 2], w1 = wtb[t * 2 + 1];
    float m0x = 0.f, m0y = 0.f, m0z = 0.f, m0w = 0.f;
    float m1x = 0.f, m1y = 0.f, m1z = 0.f, m1w = 0.f;
#pragma unroll
    for (int k = 0; k < 4; k++) {
        short4v v0 = *(const short4v*)(pout + ((size_t)k * (2 * T_) + s0) * HID_ + d);
        short4v v1 = *(const short4v*)(pout + ((size_t)k * (2 * T_) + s1) * HID_ + d);
        m0x += bf2f(v0[0]); m0y += bf2f(v0[1]); m0z += bf2f(v0[2]); m0w += bf2f(v0[3]);
        m1x += bf2f(v1[0]); m1y += bf2f(v1[1]); m1z += bf2f(v1[2]); m1w += bf2f(v1[3]);
    }
    r.x += w0 * m0x + w1 * m1x;
    r.y += w0 * m0y + w1 * m1y;
    r.z += w0 * m0z + w1 * m1z;
    r.w += w0 * m0w + w1 * m1w;
    *(float4*)(out + (size_t)t * HID_ + d) = r;
}

// ---------------- Fallback (old) MoE kernels ----------------
__global__ __launch_bounds__(256) void moe_gemm13_mfma(const float* __restrict__ X,
                                                       const float* __restrict__ w1,
                                                       const float* __restrict__ w3,
                                                       const int* __restrict__ tok_list,
                                                       const int* __restrict__ ebase,
                                                       const int* __restrict__ counts,
                                                       __hip_bfloat16* __restrict__ h13b) {
    int e = blockIdx.z;
    int cnt = counts[e];
    int bm = blockIdx.y * 128;
    if (bm >= cnt) return;
    int base = ebase[e];
    int bn = blockIdx.x * 128;

    __shared__ alignas(16) short Xa[128 * 40];
    __shared__ alignas(16) short W1s[128 * 40];
    __shared__ alignas(16) short W3s[128 * 40];

    int tid = threadIdx.x;
    int sr = tid >> 1;
    int scb = (tid & 1) * 16;

    int lrA = bm + sr;
    int tok = (lrA < cnt) ? tok_list[base + lrA] : 0;
    const float* Arow  = X + (size_t)tok * HID_ + scb;
    const float* B1row = w1 + (size_t)e * INTER_ * HID_ + (size_t)(bn + sr) * HID_ + scb;
    const float* B3row = w3 + (size_t)e * INTER_ * HID_ + (size_t)(bn + sr) * HID_ + scb;
    short* XaW = Xa  + sr * 40 + scb;
    short* W1w = W1s + sr * 40 + scb;
    short* W3w = W3s + sr * 40 + scb;

    int wvid = tid >> 6, lane = tid & 63;
    int wm = (wvid >> 1) * 64, wn = (wvid & 1) * 64;
    int l15 = lane & 15, quad = lane >> 4;

    const short* XaR = Xa  + (wm + l15) * 40 + quad * 8;
    const short* W1r = W1s + (wn + l15) * 40 + quad * 8;
    const short* W3r = W3s + (wn + l15) * 40 + quad * 8;

    floatx4 acc1[4][4], acc3[4][4];
#pragma unroll
    for (int i = 0; i < 4; i++)
#pragma unroll
        for (int j = 0; j < 4; j++) { acc1[i][j] = (floatx4)0.f; acc3[i][j] = (floatx4)0.f; }

    for (int k0 = 0; k0 < HID_; k0 += 32) {
        float4 f0 = *(const float4*)(Arow + k0);
        float4 f1 = *(const float4*)(Arow + k0 + 4);
        float4 f2 = *(const float4*)(Arow + k0 + 8);
        float4 f3 = *(const float4*)(Arow + k0 + 12);
        float4 g0 = *(const float4*)(B1row + k0);
        float4 g1 = *(const float4*)(B1row + k0 + 4);
        float4 g2 = *(const float4*)(B1row + k0 + 8);
        float4 g3 = *(const float4*)(B1row + k0 + 12);
        float4 h0 = *(const float4*)(B3row + k0);
        float4 h1 = *(const float4*)(B3row + k0 + 4);
        float4 h2 = *(const float4*)(B3row + k0 + 8);
        float4 h3 = *(const float4*)(B3row + k0 + 12);
        cvt_store16(XaW, f0, f1, f2, f3);
        cvt_store16(W1w, g0, g1, g2, g3);
        cvt_store16(W3w, h0, h1, h2, h3);
        __syncthreads();

        short8 af[4], b1f[4], b3f[4];
#pragma unroll
        for (int i = 0; i < 4; i++) af[i] = *(const short8*)(XaR + i * 16 * 40);
#pragma unroll
        for (int j = 0; j < 4; j++) {
            b1f[j] = *(const short8*)(W1r + j * 16 * 40);
            b3f[j] = *(const short8*)(W3r + j * 16 * 40);
        }
#pragma unroll
        for (int i = 0; i < 4; i++)
#pragma unroll
            for (int j = 0; j < 4; j++) {
                acc1[i][j] = __builtin_amdgcn_mfma_f32_16x16x32_bf16(af[i], b1f[j], acc1[i][j], 0, 0, 0);
                acc3[i][j] = __builtin_amdgcn_mfma_f32_16x16x32_bf16(af[i], b3f[j], acc3[i][j], 0, 0, 0);
            }
        __syncthreads();
    }

#pragma unroll
    for (int i = 0; i < 4; i++) {
#pragma unroll
        for (int reg = 0; reg < 4; reg++) {
            int lrow = bm + wm + i * 16 + quad * 4 + reg;
            if (lrow >= cnt) continue;
            size_t rowoff = (size_t)(base + lrow) * INTER_;
#pragma unroll
            for (int j = 0; j < 4; j++) {
                float a = acc1[i][j][reg];
                float v = (a / (1.f + __expf(-a))) * acc3[i][j][reg];
                h13b[rowoff + bn + wn + j * 16 + l15] = __float2bfloat16(v);
            }
        }
    }
}

__global__ __launch_bounds__(256) void moe_gemm2_mfma(const __hip_bfloat16* __restrict__ h13b,
                                                      const float* __restrict__ w2,
                                                      const int* __restrict__ tok_list,
                                                      const float* __restrict__ wt_list,
                                                      const int* __restrict__ ebase,
                                                      const int* __restrict__ counts,
                                                      float* __restrict__ out) {
    int e = blockIdx.z;
    int cnt = counts[e];
    int bm = blockIdx.y * 128;
    if (bm >= cnt) return;
    int base = ebase[e];
    int bn = blockIdx.x * 128;

    __shared__ alignas(16) short Xa[128 * 40];
    __shared__ alignas(16) short Ws[128 * 40];

    int tid = threadIdx.x;
    int sr = tid >> 1;
    int scb = (tid & 1) * 16;

    int lrA = bm + sr;
    int slot = base + ((lrA < cnt) ? lrA : 0);
    const short* Arow = (const short*)h13b + (size_t)slot * INTER_ + scb;
    const float* Brow = w2 + (size_t)e * HID_ * INTER_ + (size_t)(bn + sr) * INTER_ + scb;
    short* XaW = Xa + sr * 40 + scb;
    short* WsW = Ws + sr * 40 + scb;

    int wvid = tid >> 6, lane = tid & 63;
    int wm = (wvid >> 1) * 64, wn = (wvid & 1) * 64;
    int l15 = lane & 15, quad = lane >> 4;

    const short* XaR = Xa + (wm + l15) * 40 + quad * 8;
    const short* WsR = Ws + (wn + l15) * 40 + quad * 8;

    floatx4 acc[4][4];
#pragma unroll
    for (int i = 0; i < 4; i++)
#pragma unroll
        for (int j = 0; j < 4; j++) acc[i][j] = (floatx4)0.f;

    for (int k0 = 0; k0 < INTER_; k0 += 32) {
        short8 v0 = *(const short8*)(Arow + k0);
        short8 v1 = *(const short8*)(Arow + k0 + 8);
        float4 g0 = *(const float4*)(Brow + k0);
        float4 g1 = *(const float4*)(Brow + k0 + 4);
        float4 g2 = *(const float4*)(Brow + k0 + 8);
        float4 g3 = *(const float4*)(Brow + k0 + 12);
        *(short8*)XaW = v0;
        *(short8*)(XaW + 8) = v1;
        cvt_store16(WsW, g0, g1, g2, g3);
        __syncthreads();

        short8 af[4], bf_[4];
#pragma unroll
        for (int i = 0; i < 4; i++) af[i] = *(const short8*)(XaR + i * 16 * 40);
#pragma unroll
        for (int j = 0; j < 4; j++) bf_[j] = *(const short8*)(WsR + j * 16 * 40);
#pragma unroll
        for (int i = 0; i < 4; i++)
#pragma unroll
            for (int j = 0; j < 4; j++)
                acc[i][j] = __builtin_amdgcn_mfma_f32_16x16x32_bf16(af[i], bf_[j], acc[i][j], 0, 0, 0);
        __syncthreads();
    }

#pragma unroll
    for (int i = 0; i < 4; i++) {
#pragma unroll
        for (int reg = 0; reg < 4; reg++) {
            int lrow = bm + wm + i * 16 + quad * 4 + reg;
            if (lrow >= cnt) continue;
            int tok = tok_list[base + lrow];
            float w = wt_list[base + lrow];
            size_t rowoff = (size_t)tok * HID_;
#pragma unroll
            for (int j = 0; j < 4; j++)
                atomicAdd(&out[rowoff + bn + wn + j * 16 + l15], w * acc[i][j][reg]);
        }
    }
}

__global__ void copy4_kernel(const float* __restrict__ src, float* __restrict__ dst, int n4) {
    int i = blockIdx.x * blockDim.x + threadIdx.x;
    if (i < n4) ((float4*)dst)[i] = ((const float4*)src)[i];
}

extern "C" void kernel_launch(void* const* d_in, const int* in_sizes, int n_in,
                              void* d_out, int out_size, void* d_ws, size_t ws_size,
                              hipStream_t stream) {
    const float* h      = (const float*)d_in[0];
    const int*   pos    = (const int*)d_in[1];
    const float* wq     = (const float*)d_in[2];
    const float* wk     = (const float*)d_in[3];
    const float* wv     = (const float*)d_in[4];
    const float* wo     = (const float*)d_in[5];
    const float* gate_w = (const float*)d_in[6];
    const float* w1     = (const float*)d_in[7];
    const float* w2     = (const float*)d_in[8];
    const float* w3     = (const float*)d_in[9];
    const float* ln1_w  = (const float*)d_in[10];
    const float* ln2_w  = (const float*)d_in[11];
    float* out = (float*)d_out;

    float* ws = (float*)d_ws;
    const size_t M1 = 1024 * 1024;
    float* xn1 = ws;                 // 2M floats (alias: ob)
    float* ob  = ws;
    float* qb  = ws + 2 * M1;        // 2M (alias: h2)
    float* h2  = ws + 2 * M1;
    float* kb  = ws + 4 * M1;        // 0.5M
    float* vb  = ws + 4 * M1 + M1 / 2; // 0.5M
    float* xn2 = ws + 5 * M1;        // 2M
    __hip_bfloat16* h13b = (__hip_bfloat16*)(ws + 7 * M1);  // ends at 14.34M floats
    float* smallf = ws + 14 * M1 + M1 / 2;
    int*   sel      = (int*)smallf;
    float* wtb      = smallf + 4096;
    int*   counts   = (int*)(smallf + 8192);
    int*   ebase    = (int*)(smallf + 8192 + 16);
    int*   cursor   = (int*)(smallf + 8192 + 32);
    int*   tok_list = (int*)(smallf + 8192 + 64);
    float* wt_list  = smallf + 8192 + 64 + 4352;
    int*   slot_list= (int*)(smallf + 8192 + 64 + 8704);   // 4096 ints

    // new-path bf16 staging buffers (beyond 15M floats)
    const size_t WELEM = (size_t)E_ * INTER_ * HID_;       // 29,360,128 bf16 elems per weight
    short* xn2b = (short*)(ws + 15 * M1);                  // T*HID bf16
    short* w1bb = (short*)(ws + 16 * M1);                  // WELEM bf16
    short* w3bb = w1bb + WELEM;                            // WELEM bf16
    short* w2bb = w1bb;                                    // reuse w1b slot after gemm13
    short* pout = w3bb;                                    // 4*4096*1024 bf16 = 16.8M shorts, fits
                                                           // w3bb (dead after gemm13); stream-ordered
    // attention + projection bf16 buffers: alias w1bb region (all consumed BEFORE
    // cvt(w1) runs; single stream => strictly ordered, safe)
    short* qbh  = (short*)(ws + 16 * M1);                  // 2M shorts
    short* kbh  = (short*)(ws + 17 * M1);                  // 0.5M shorts
    short* vbh  = (short*)(ws + 17 * M1 + M1 / 4);         // 0.5M shorts
    short* wqb  = (short*)(ws + 17 * M1 + M1 / 2);         // 1M shorts (1024x1024)
    short* wkb  = (short*)(ws + 18 * M1);                  // 0.25M shorts
    short* wvb  = (short*)(ws + 18 * M1 + M1 / 8);         // 0.25M shorts
    short* wob  = (short*)(ws + 18 * M1 + M1 / 4);         // 1M shorts
    short* xn1b = (short*)(ws + 18 * M1 + 3 * M1 / 4);     // 2M shorts
    short* obh  = (short*)(ws + 19 * M1 + 3 * M1 / 4);     // 2M shorts -> ends 20.75M floats
    const size_t need_bytes = (16 * M1 + WELEM) * sizeof(float);  // ~181.4 MB
    bool big = ws_size >= need_bytes;

    hipLaunchKernelGGL(init_counts_kernel, dim3(1), dim3(64), 0, stream, counts);
    hipLaunchKernelGGL(rmsnorm_kernel, dim3(T_), dim3(256), 0, stream, h, ln1_w, xn1);

    if (big) {
        hipLaunchKernelGGL(cvt_bf16_kernel, dim3(512), dim3(256), 0, stream, wq, wqb, NH_ * HD_ * HID_ / 8);
        hipLaunchKernelGGL(cvt_bf16_kernel, dim3(128), dim3(256), 0, stream, wk, wkb, NKV_ * HD_ * HID_ / 8);
        hipLaunchKernelGGL(cvt_bf16_kernel, dim3(128), dim3(256), 0, stream, wv, wvb, NKV_ * HD_ * HID_ / 8);
        hipLaunchKernelGGL(cvt_bf16_kernel, dim3(512), dim3(256), 0, stream, wo, wob, HID_ * NH_ * HD_ / 8);
        hipLaunchKernelGGL(cvt_bf16_kernel, dim3(1024), dim3(256), 0, stream, xn1, xn1b, T_ * HID_ / 8);
        hipLaunchKernelGGL(gemm_bf16_v2, dim3(NH_ * HD_ / 128, T_ / 128), dim3(256), 0, stream,
                           xn1b, wqb, qb, (const float*)nullptr, T_, NH_ * HD_, HID_);
        hipLaunchKernelGGL(gemm_bf16_v2, dim3(NKV_ * HD_ / 128, T_ / 128), dim3(256), 0, stream,
                           xn1b, wkb, kb, (const float*)nullptr, T_, NKV_ * HD_, HID_);
        hipLaunchKernelGGL(gemm_bf16_v2, dim3(NKV_ * HD_ / 128, T_ / 128), dim3(256), 0, stream,
                           xn1b, wvb, vb, (const float*)nullptr, T_, NKV_ * HD_, HID_);
        {
            int tot = T_ * (NH_ + NKV_) * 32;
            hipLaunchKernelGGL(rope_kernel, dim3((tot + 255) / 256), dim3(256), 0, stream, qb, kb, pos);
        }
        hipLaunchKernelGGL(cvt_bf16_kernel, dim3(1024), dim3(256), 0, stream, qb, qbh, T_ * NH_ * HD_ / 8);
        hipLaunchKernelGGL(cvt_bf16_kernel, dim3(256),  dim3(256), 0, stream, kb, kbh, T_ * NKV_ * HD_ / 8);
        hipLaunchKernelGGL(cvt_bf16_kernel, dim3(256),  dim3(256), 0, stream, vb, vbh, T_ * NKV_ * HD_ / 8);
        hipLaunchKernelGGL(flash_attn_mfma, dim3(32 * 16), dim3(256), 0, stream, qbh, kbh, vbh, obh);
        hipLaunchKernelGGL(gemm_bf16_v2, dim3(HID_ / 128, T_ / 128), dim3(256), 0, stream,
                           obh, wob, h2, h, T_, HID_, NH_ * HD_);
    } else {
        hipLaunchKernelGGL(gemm_f32, dim3(16, 32), dim3(256), 0, stream, xn1, wq, qb, (const float*)nullptr, T_, NH_ * HD_, HID_);
        hipLaunchKernelGGL(gemm_f32, dim3(4, 32),  dim3(256), 0, stream, xn1, wk, kb, (const float*)nullptr, T_, NKV_ * HD_, HID_);
        hipLaunchKernelGGL(gemm_f32, dim3(4, 32),  dim3(256), 0, stream, xn1, wv, vb, (const float*)nullptr, T_, NKV_ * HD_, HID_);
        {
            int tot = T_ * (NH_ + NKV_) * 32;
            hipLaunchKernelGGL(rope_kernel, dim3((tot + 255) / 256), dim3(256), 0, stream, qb, kb, pos);
        }
        hipLaunchKernelGGL(flash_attn_kernel, dim3(32 * 16), dim3(256), 0, stream, qb, kb, vb, ob);
        hipLaunchKernelGGL(gemm_f32, dim3(16, 32), dim3(256), 0, stream, ob, wo, h2, h, T_, HID_, NH_ * HD_);
    }

    hipLaunchKernelGGL(rmsnorm_kernel, dim3(T_), dim3(256), 0, stream, h2, ln2_w, xn2);
    hipLaunchKernelGGL(gating_kernel, dim3(T_), dim3(64), 0, stream, xn2, gate_w, sel, wtb, counts);
    hipLaunchKernelGGL(prefix_kernel, dim3(1), dim3(64), 0, stream, counts, ebase, cursor);
    hipLaunchKernelGGL(scatter_kernel, dim3((T_ + 255) / 256), dim3(256), 0, stream, sel, wtb, cursor,
                       tok_list, wt_list, slot_list);

    if (big) {
        const int n8w = (int)(WELEM / 8);
        hipLaunchKernelGGL(cvt_bf16_kernel, dim3(2048), dim3(256), 0, stream, w1, w1bb, n8w);
        hipLaunchKernelGGL(cvt_bf16_kernel, dim3(2048), dim3(256), 0, stream, w3, w3bb, n8w);
        hipLaunchKernelGGL(cvt_bf16_kernel, dim3(256),  dim3(256), 0, stream, xn2, xn2b, T_ * HID_ / 8);
        hipLaunchKernelGGL(moe_gemm13_v2, dim3(INTER_ / 128, 16, E_), dim3(256), 0, stream,
                           xn2b, w1bb, w3bb, tok_list, ebase, counts, h13b);
        hipLaunchKernelGGL(cvt_bf16_kernel, dim3(2048), dim3(256), 0, stream, w2, w2bb, n8w);
        // gemm2 v4: split-K=4, non-atomic bf16 partials into pout (overwrites dead w3bb)
        hipLaunchKernelGGL(moe_gemm2_v4, dim3(HID_ / 128, 16, E_ * 4), dim3(256), 0, stream,
                           (const short*)h13b, w2bb, ebase, counts, pout);
        // combine: out = h2 + sum_j wt_j * sum_k pout[k][slot_j]
        hipLaunchKernelGGL(moe_combine_kernel, dim3(T_), dim3(256), 0, stream,
                           h2, pout, slot_list, wtb, out);
    } else {
        hipLaunchKernelGGL(moe_gemm13_mfma, dim3(INTER_ / 128, 16, E_), dim3(256), 0, stream,
                           xn2, w1, w3, tok_list, ebase, counts, h13b);
        hipLaunchKernelGGL(copy4_kernel, dim3((T_ * HID_ / 4 + 255) / 256), dim3(256), 0, stream, h2, out, T_ * HID_ / 4);
        hipLaunchKernelGGL(moe_gemm2_mfma, dim3(HID_ / 128, 16, E_), dim3(256), 0, stream,
                           h13b, w2, tok_list, wt_list, ebase, counts, out);
    }
}

// Round 7
// 773.307 us; speedup vs baseline: 1.2014x; 1.0526x over previous
//
#include <hip/hip_runtime.h>
#include <hip/hip_bf16.h>
#include <math.h>

#define T_    2048
#define HID_  1024
#define NH_   16
#define NKV_  4
#define HD_   64
#define E_    8
#define TOPK_ 2
#define INTER_ 3584
#define EPS_  1e-6f
#define QKVW_ 1536   // NH*HD + 2*NKV*HD

typedef __attribute__((ext_vector_type(8))) short short8;
typedef __attribute__((ext_vector_type(4))) short short4v;
typedef __attribute__((ext_vector_type(4))) float floatx4;

__device__ inline short f2bf(float f) {
    __hip_bfloat16 b = __float2bfloat16(f);
    return *reinterpret_cast<short*>(&b);
}

__device__ inline float bf2f(short s) {
    __hip_bfloat16 b = *reinterpret_cast<__hip_bfloat16*>(&s);
    return __bfloat162float(b);
}

__device__ inline void cvt_store16(short* dst, float4 a, float4 b, float4 c, float4 d) {
    short8 lo, hi;
    lo[0] = f2bf(a.x); lo[1] = f2bf(a.y); lo[2] = f2bf(a.z); lo[3] = f2bf(a.w);
    lo[4] = f2bf(b.x); lo[5] = f2bf(b.y); lo[6] = f2bf(b.z); lo[7] = f2bf(b.w);
    hi[0] = f2bf(c.x); hi[1] = f2bf(c.y); hi[2] = f2bf(c.z); hi[3] = f2bf(c.w);
    hi[4] = f2bf(d.x); hi[5] = f2bf(d.y); hi[6] = f2bf(d.z); hi[7] = f2bf(d.w);
    *(short8*)dst = lo;
    *(short8*)(dst + 8) = hi;
}

// async global->LDS, 16B per lane. LDS dest must be wave-uniform-base + lane*16.
__device__ inline void async_copy16(short* lds, const short* g) {
    __builtin_amdgcn_global_load_lds((const __attribute__((address_space(1))) void*)g,
                                     (__attribute__((address_space(3))) void*)lds, 16, 0, 0);
}

// ---------------- RMSNorm variants ----------------
__global__ __launch_bounds__(256) void rmsnorm_kernel(const float* __restrict__ x,
                                                      const float* __restrict__ w,
                                                      float* __restrict__ o) {
    int t = blockIdx.x;
    const float* xr = x + (size_t)t * HID_;
    float s = 0.f;
    for (int d = threadIdx.x; d < HID_; d += 256) { float v = xr[d]; s += v * v; }
    __shared__ float red[256];
    red[threadIdx.x] = s; __syncthreads();
    for (int off = 128; off > 0; off >>= 1) {
        if (threadIdx.x < off) red[threadIdx.x] += red[threadIdx.x + off];
        __syncthreads();
    }
    float inv = rsqrtf(red[0] / (float)HID_ + EPS_);
    for (int d = threadIdx.x; d < HID_; d += 256)
        o[(size_t)t * HID_ + d] = w[d] * xr[d] * inv;
}

__global__ __launch_bounds__(256) void rmsnorm_bf16_kernel(const float* __restrict__ x,
                                                           const float* __restrict__ w,
                                                           short* __restrict__ o) {
    int t = blockIdx.x;
    const float* xr = x + (size_t)t * HID_;
    float s = 0.f;
    for (int d = threadIdx.x; d < HID_; d += 256) { float v = xr[d]; s += v * v; }
    __shared__ float red[256];
    red[threadIdx.x] = s; __syncthreads();
    for (int off = 128; off > 0; off >>= 1) {
        if (threadIdx.x < off) red[threadIdx.x] += red[threadIdx.x + off];
        __syncthreads();
    }
    float inv = rsqrtf(red[0] / (float)HID_ + EPS_);
    for (int d = threadIdx.x; d < HID_; d += 256)
        o[(size_t)t * HID_ + d] = f2bf(w[d] * xr[d] * inv);
}

__global__ __launch_bounds__(256) void rmsnorm_dual_kernel(const float* __restrict__ x,
                                                           const float* __restrict__ w,
                                                           float* __restrict__ of,
                                                           short* __restrict__ ob) {
    int t = blockIdx.x;
    const float* xr = x + (size_t)t * HID_;
    float s = 0.f;
    for (int d = threadIdx.x; d < HID_; d += 256) { float v = xr[d]; s += v * v; }
    __shared__ float red[256];
    red[threadIdx.x] = s; __syncthreads();
    for (int off = 128; off > 0; off >>= 1) {
        if (threadIdx.x < off) red[threadIdx.x] += red[threadIdx.x + off];
        __syncthreads();
    }
    float inv = rsqrtf(red[0] / (float)HID_ + EPS_);
    for (int d = threadIdx.x; d < HID_; d += 256) {
        float v = w[d] * xr[d] * inv;
        of[(size_t)t * HID_ + d] = v;
        ob[(size_t)t * HID_ + d] = f2bf(v);
    }
}

// ---------------- Generic fp32 GEMM (fallback path only) ----------------
__global__ __launch_bounds__(256) void gemm_f32(const float* __restrict__ A,
                                                const float* __restrict__ B,
                                                float* __restrict__ C,
                                                const float* __restrict__ addsrc,
                                                int M, int N, int K) {
    __shared__ float As[16][65];
    __shared__ float Bs[16][65];
    int tid = threadIdx.x;
    int tx = tid & 15, ty = tid >> 4;
    int bm = blockIdx.y * 64, bn = blockIdx.x * 64;
    float acc[4][4];
#pragma unroll
    for (int i = 0; i < 4; i++)
#pragma unroll
        for (int j = 0; j < 4; j++) acc[i][j] = 0.f;

    int mL[4], kL[4];
#pragma unroll
    for (int l = 0; l < 4; l++) { int idx = tid + l * 256; mL[l] = idx >> 4; kL[l] = idx & 15; }

    for (int k0 = 0; k0 < K; k0 += 16) {
#pragma unroll
        for (int l = 0; l < 4; l++) {
            int m = mL[l], kk = kL[l];
            int gr = bm + m;
            As[kk][m] = (gr < M) ? A[(size_t)gr * K + k0 + kk] : 0.f;
            int gc = bn + m;
            Bs[kk][m] = (gc < N) ? B[(size_t)gc * K + k0 + kk] : 0.f;
        }
        __syncthreads();
#pragma unroll
        for (int kk = 0; kk < 16; kk++) {
            float a[4], b[4];
#pragma unroll
            for (int i = 0; i < 4; i++) a[i] = As[kk][ty * 4 + i];
#pragma unroll
            for (int j = 0; j < 4; j++) b[j] = Bs[kk][tx * 4 + j];
#pragma unroll
            for (int i = 0; i < 4; i++)
#pragma unroll
                for (int j = 0; j < 4; j++) acc[i][j] += a[i] * b[j];
        }
        __syncthreads();
    }
#pragma unroll
    for (int i = 0; i < 4; i++) {
        int r = bm + ty * 4 + i;
        if (r >= M) continue;
#pragma unroll
        for (int j = 0; j < 4; j++) {
            int c = bn + tx * 4 + j;
            if (c >= N) continue;
            float v = acc[i][j];
            if (addsrc) v += addsrc[(size_t)r * N + c];
            C[(size_t)r * N + c] = v;
        }
    }
}

// ---------------- bf16 MFMA GEMM: C[M,N] = A[M,K] @ B[N,K]^T (+addsrc), fp32 out ----------------
// Bank-conflict swizzle: LDS position (r, c-chunk) holds original element (r, c ^ ((r&1)*16)).
// Achieved via XOR on global SOURCE address (gload_lds writes linearly) + XOR on ds_read addr.
__global__ __launch_bounds__(256, 2) void gemm_bf16_v2(const short* __restrict__ A,
                                                       const short* __restrict__ B,
                                                       float* __restrict__ C,
                                                       const float* __restrict__ addsrc,
                                                       int M, int N, int K) {
    int bm = blockIdx.y * 128;
    int bn = blockIdx.x * 128;

    __shared__ alignas(16) short lds[2][2][128 * 32];  // 32 KiB

    int tid = threadIdx.x;
    int sr = tid >> 2;
    int sc = ((tid & 3) * 8) ^ ((sr & 1) << 4);   // swizzled source col
    int ldst = tid * 8;

    const short* aG0 = A + (size_t)(bm + sr) * K + sc;
    const short* aG1 = aG0 + (size_t)64 * K;
    const short* bG0 = B + (size_t)(bn + sr) * K + sc;
    const short* bG1 = bG0 + (size_t)64 * K;

    int wvid = tid >> 6, lane = tid & 63;
    int wm = (wvid >> 1) * 64, wn = (wvid & 1) * 64;
    int l15 = lane & 15, quad = lane >> 4;
    int rcol = (quad * 8) ^ ((l15 & 1) << 4);     // swizzled read col

    floatx4 acc[4][4];
#pragma unroll
    for (int i = 0; i < 4; i++)
#pragma unroll
        for (int j = 0; j < 4; j++) acc[i][j] = (floatx4)0.f;

#define STAGEG(b, k0) do {                                          \
        async_copy16(&lds[b][0][ldst],        aG0 + (k0));          \
        async_copy16(&lds[b][0][ldst + 2048], aG1 + (k0));          \
        async_copy16(&lds[b][1][ldst],        bG0 + (k0));          \
        async_copy16(&lds[b][1][ldst + 2048], bG1 + (k0));          \
    } while (0)

    STAGEG(0, 0);
    __syncthreads();

    int cur = 0;
    for (int k0 = 0; k0 < K; k0 += 32) {
        if (k0 + 32 < K) STAGEG(cur ^ 1, k0 + 32);

        const short* XaR = &lds[cur][0][(wm + l15) * 32 + rcol];
        const short* WsR = &lds[cur][1][(wn + l15) * 32 + rcol];
        short8 af[4], bf_[4];
#pragma unroll
        for (int i = 0; i < 4; i++) af[i] = *(const short8*)(XaR + i * 16 * 32);
#pragma unroll
        for (int j = 0; j < 4; j++) bf_[j] = *(const short8*)(WsR + j * 16 * 32);
#pragma unroll
        for (int i = 0; i < 4; i++)
#pragma unroll
            for (int j = 0; j < 4; j++)
                acc[i][j] = __builtin_amdgcn_mfma_f32_16x16x32_bf16(af[i], bf_[j], acc[i][j], 0, 0, 0);
        __syncthreads();
        cur ^= 1;
    }
#undef STAGEG

#pragma unroll
    for (int i = 0; i < 4; i++) {
#pragma unroll
        for (int reg = 0; reg < 4; reg++) {
            int r = bm + wm + i * 16 + quad * 4 + reg;
            size_t rowoff = (size_t)r * N;
#pragma unroll
            for (int j = 0; j < 4; j++) {
                int c = bn + wn + j * 16 + l15;
                float v = acc[i][j][reg];
                if (addsrc) v += addsrc[rowoff + c];
                C[rowoff + c] = v;
            }
        }
    }
}

// ---------------- RoPE: separate q/k (fallback) ----------------
__global__ void rope_kernel(float* __restrict__ qb, float* __restrict__ kb,
                            const int* __restrict__ pos_ids) {
    int idx = blockIdx.x * blockDim.x + threadIdx.x;
    const int totq = T_ * NH_ * 32;
    const int totk = T_ * NKV_ * 32;
    if (idx >= totq + totk) return;
    float* buf; int t, hh, i, hw;
    if (idx < totq) { buf = qb; hw = NH_;  t = idx / (NH_ * 32); int r = idx % (NH_ * 32); hh = r / 32; i = r % 32; }
    else { idx -= totq; buf = kb; hw = NKV_; t = idx / (NKV_ * 32); int r = idx % (NKV_ * 32); hh = r / 32; i = r % 32; }
    float pos = (float)pos_ids[t];
    float inv = expf(-(float)i * (13.815510558f / 32.0f));
    float fr = pos * inv;
    float c = cosf(fr), s = sinf(fr);
    size_t base = (size_t)t * hw * 64 + (size_t)hh * 64;
    float x1 = buf[base + i], x2 = buf[base + i + 32];
    buf[base + i]      = x1 * c - x2 * s;
    buf[base + i + 32] = x2 * c + x1 * s;
}

// ---------------- RoPE on combined qkv buffer [T][1536] ----------------
__global__ void rope_qkv_kernel(float* __restrict__ qkv, const int* __restrict__ pos_ids) {
    int idx = blockIdx.x * blockDim.x + threadIdx.x;
    const int totq = T_ * NH_ * 32;
    const int totk = T_ * NKV_ * 32;
    if (idx >= totq + totk) return;
    int t, hh, i; size_t base;
    if (idx < totq) {
        t = idx / (NH_ * 32); int r = idx % (NH_ * 32); hh = r / 32; i = r % 32;
        base = (size_t)t * QKVW_ + hh * 64;
    } else {
        idx -= totq;
        t = idx / (NKV_ * 32); int r = idx % (NKV_ * 32); hh = r / 32; i = r % 32;
        base = (size_t)t * QKVW_ + NH_ * HD_ + hh * 64;
    }
    float pos = (float)pos_ids[t];
    float inv = expf(-(float)i * (13.815510558f / 32.0f));
    float fr = pos * inv;
    float c = cosf(fr), s = sinf(fr);
    float x1 = qkv[base + i], x2 = qkv[base + i + 32];
    qkv[base + i]      = x1 * c - x2 * s;
    qkv[base + i + 32] = x2 * c + x1 * s;
}

// ---------------- Flash attention: bf16 MFMA on combined qkv layout ----------------
__global__ __launch_bounds__(256) void flash_attn_mfma_c(const short* __restrict__ qkvh,
                                                         short* __restrict__ obh) {
    __shared__ alignas(16) short Ks[64][80];
    __shared__ alignas(16) short Vt[64][80];
    __shared__ alignas(16) short Ps[64][80];

    int bid = blockIdx.x;
    int h = bid & 15;
    int qr = bid >> 4;
    int qt = (qr & 1) ? (31 - (qr >> 1)) : (qr >> 1);
    int q0 = qt * 64;
    int kvh = h >> 2;
    int tid = threadIdx.x;
    int w = tid >> 6, lane = tid & 63;
    int l15 = lane & 15, quad = lane >> 4;
    int str = tid >> 2, stc = tid & 3;

    const int KOFF = NH_ * HD_ + kvh * HD_;          // k base within row
    const int VOFF = NH_ * HD_ + NKV_ * HD_ + kvh * HD_;

    short8 aq0, aq1;
    {
        const short* qrow = qkvh + (size_t)(q0 + 16 * w + l15) * QKVW_ + h * HD_ + quad * 8;
        aq0 = *(const short8*)(qrow);
        aq1 = *(const short8*)(qrow + 32);
    }

    floatx4 o_acc[4];
    float m_i[4], l_i[4];
#pragma unroll
    for (int j = 0; j < 4; j++) o_acc[j] = (floatx4)0.f;
#pragma unroll
    for (int r = 0; r < 4; r++) { m_i[r] = -INFINITY; l_i[r] = 0.f; }

    int nt = q0 / 64 + 1;

    const short* kg = qkvh + (size_t)str * QKVW_ + KOFF + stc * 8;
    const short* vg = qkvh + (size_t)str * QKVW_ + VOFF + stc * 8;
    short8 kr0 = *(const short8*)kg;
    short8 kr1 = *(const short8*)(kg + 32);
    short8 vr0 = *(const short8*)vg;
    short8 vr1 = *(const short8*)(vg + 32);

    for (int it = 0; it < nt; ++it) {
        int t0 = it * 64;
        __syncthreads();
        *(short8*)&Ks[str][stc * 8]      = kr0;
        *(short8*)&Ks[str][32 + stc * 8] = kr1;
#pragma unroll
        for (int i = 0; i < 8; i++) {
            Vt[stc * 8 + i][str]      = vr0[i];
            Vt[32 + stc * 8 + i][str] = vr1[i];
        }
        if (it + 1 < nt) {
            const short* kgn = qkvh + (size_t)(t0 + 64 + str) * QKVW_ + KOFF + stc * 8;
            const short* vgn = qkvh + (size_t)(t0 + 64 + str) * QKVW_ + VOFF + stc * 8;
            kr0 = *(const short8*)kgn;
            kr1 = *(const short8*)(kgn + 32);
            vr0 = *(const short8*)vgn;
            vr1 = *(const short8*)(vgn + 32);
        }
        __syncthreads();

        floatx4 s[4];
#pragma unroll
        for (int j = 0; j < 4; j++) s[j] = (floatx4)0.f;
        __builtin_amdgcn_s_setprio(1);
#pragma unroll
        for (int j = 0; j < 4; j++) {
            short8 bk0 = *(const short8*)&Ks[16 * j + l15][quad * 8];
            short8 bk1 = *(const short8*)&Ks[16 * j + l15][32 + quad * 8];
            s[j] = __builtin_amdgcn_mfma_f32_16x16x32_bf16(aq0, bk0, s[j], 0, 0, 0);
            s[j] = __builtin_amdgcn_mfma_f32_16x16x32_bf16(aq1, bk1, s[j], 0, 0, 0);
        }
        __builtin_amdgcn_s_setprio(0);

        bool diag = (t0 == q0);
#pragma unroll
        for (int j = 0; j < 4; j++)
#pragma unroll
            for (int reg = 0; reg < 4; reg++) {
                s[j][reg] *= 0.125f;
                if (diag && (16 * j + l15 > 16 * w + quad * 4 + reg)) s[j][reg] = -INFINITY;
            }

#pragma unroll
        for (int reg = 0; reg < 4; reg++) {
            float mx = fmaxf(fmaxf(s[0][reg], s[1][reg]), fmaxf(s[2][reg], s[3][reg]));
#pragma unroll
            for (int off = 8; off >= 1; off >>= 1) mx = fmaxf(mx, __shfl_xor(mx, off));
            float mn = fmaxf(m_i[reg], mx);
            float alpha = __expf(m_i[reg] - mn);
            float rs = 0.f;
#pragma unroll
            for (int j = 0; j < 4; j++) { float p = __expf(s[j][reg] - mn); s[j][reg] = p; rs += p; }
#pragma unroll
            for (int off = 8; off >= 1; off >>= 1) rs += __shfl_xor(rs, off);
            l_i[reg] = l_i[reg] * alpha + rs;
            m_i[reg] = mn;
#pragma unroll
            for (int j = 0; j < 4; j++) o_acc[j][reg] *= alpha;
        }

#pragma unroll
        for (int j = 0; j < 4; j++)
#pragma unroll
            for (int reg = 0; reg < 4; reg++)
                Ps[16 * w + quad * 4 + reg][16 * j + l15] = f2bf(s[j][reg]);
        __asm__ volatile("s_waitcnt lgkmcnt(0)" ::: "memory");

        short8 ap0 = *(const short8*)&Ps[16 * w + l15][quad * 8];
        short8 ap1 = *(const short8*)&Ps[16 * w + l15][32 + quad * 8];
        __builtin_amdgcn_s_setprio(1);
#pragma unroll
        for (int j = 0; j < 4; j++) {
            short8 bv0 = *(const short8*)&Vt[16 * j + l15][quad * 8];
            short8 bv1 = *(const short8*)&Vt[16 * j + l15][32 + quad * 8];
            o_acc[j] = __builtin_amdgcn_mfma_f32_16x16x32_bf16(ap0, bv0, o_acc[j], 0, 0, 0);
            o_acc[j] = __builtin_amdgcn_mfma_f32_16x16x32_bf16(ap1, bv1, o_acc[j], 0, 0, 0);
        }
        __builtin_amdgcn_s_setprio(0);
    }

#pragma unroll
    for (int reg = 0; reg < 4; reg++) {
        float invl = 1.f / l_i[reg];
        size_t rbase = (size_t)(q0 + 16 * w + quad * 4 + reg) * (NH_ * HD_) + h * HD_;
#pragma unroll
        for (int j = 0; j < 4; j++)
            obh[rbase + 16 * j + l15] = f2bf(o_acc[j][reg] * invl);
    }
}

// ---------------- Flash attention (fp32 fallback) ----------------
__global__ __launch_bounds__(256) void flash_attn_kernel(const float* __restrict__ qb,
                                                         const float* __restrict__ kb,
                                                         const float* __restrict__ vb,
                                                         float* __restrict__ ob) {
    __shared__ float Qs[64][68];
    __shared__ float Ks[64][68];
    __shared__ float Vs[64][68];
    __shared__ float Ps[64][68];

    int bid = blockIdx.x;
    int h = bid & 15;
    int qr = bid >> 4;
    int qt = (qr & 1) ? (31 - (qr >> 1)) : (qr >> 1);
    int q0 = qt * 64;
    int kvh = h >> 2;
    int tid = threadIdx.x;
    int tx = tid & 15, ty = tid >> 4;

#pragma unroll
    for (int l = 0; l < 16; l++) {
        int idx = l * 256 + tid;
        int m = idx >> 6, d = idx & 63;
        Qs[d][m] = qb[(size_t)(q0 + m) * (NH_ * HD_) + h * HD_ + d];
    }

    float o_acc[4][4];
    float m_i[4], l_i[4];
#pragma unroll
    for (int i = 0; i < 4; i++) {
        m_i[i] = -INFINITY; l_i[i] = 0.f;
#pragma unroll
        for (int j = 0; j < 4; j++) o_acc[i][j] = 0.f;
    }

    for (int t0 = 0; t0 <= q0; t0 += 64) {
        __syncthreads();
#pragma unroll
        for (int l = 0; l < 16; l++) {
            int idx = l * 256 + tid;
            int m = idx >> 6, d = idx & 63;
            size_t g = (size_t)(t0 + m) * (NKV_ * HD_) + kvh * HD_ + d;
            Ks[d][m] = kb[g];
            Vs[m][d] = vb[g];
        }
        __syncthreads();

        float s[4][4];
#pragma unroll
        for (int i = 0; i < 4; i++)
#pragma unroll
            for (int j = 0; j < 4; j++) s[i][j] = 0.f;
#pragma unroll 4
        for (int kk = 0; kk < 64; kk++) {
            float4 a4 = *(const float4*)&Qs[kk][ty * 4];
            float4 b4 = *(const float4*)&Ks[kk][tx * 4];
            float a[4] = {a4.x, a4.y, a4.z, a4.w};
            float b[4] = {b4.x, b4.y, b4.z, b4.w};
#pragma unroll
            for (int i = 0; i < 4; i++)
#pragma unroll
                for (int j = 0; j < 4; j++) s[i][j] += a[i] * b[j];
        }

        bool diag = (t0 == q0);
#pragma unroll
        for (int i = 0; i < 4; i++) {
#pragma unroll
            for (int j = 0; j < 4; j++) {
                s[i][j] *= 0.125f;
                if (diag && (t0 + tx * 4 + j > q0 + ty * 4 + i)) s[i][j] = -INFINITY;
            }
        }

#pragma unroll
        for (int i = 0; i < 4; i++) {
            float mx = fmaxf(fmaxf(s[i][0], s[i][1]), fmaxf(s[i][2], s[i][3]));
#pragma unroll
            for (int off = 8; off >= 1; off >>= 1) mx = fmaxf(mx, __shfl_xor(mx, off));
            float mn = fmaxf(m_i[i], mx);
            float alpha = __expf(m_i[i] - mn);
            float rs = 0.f;
#pragma unroll
            for (int j = 0; j < 4; j++) { float p = __expf(s[i][j] - mn); s[i][j] = p; rs += p; }
#pragma unroll
            for (int off = 8; off >= 1; off >>= 1) rs += __shfl_xor(rs, off);
            l_i[i] = l_i[i] * alpha + rs;
            m_i[i] = mn;
#pragma unroll
            for (int j = 0; j < 4; j++) o_acc[i][j] *= alpha;
        }

#pragma unroll
        for (int j = 0; j < 4; j++)
#pragma unroll
            for (int i = 0; i < 4; i++)
                Ps[tx * 4 + j][ty * 4 + i] = s[i][j];
        __syncthreads();

#pragma unroll 4
        for (int kk = 0; kk < 64; kk++) {
            float4 a4 = *(const float4*)&Ps[kk][ty * 4];
            float4 b4 = *(const float4*)&Vs[kk][tx * 4];
            float a[4] = {a4.x, a4.y, a4.z, a4.w};
            float b[4] = {b4.x, b4.y, b4.z, b4.w};
#pragma unroll
            for (int i = 0; i < 4; i++)
#pragma unroll
                for (int j = 0; j < 4; j++) o_acc[i][j] += a[i] * b[j];
        }
    }

#pragma unroll
    for (int i = 0; i < 4; i++) {
        float invl = 1.f / l_i[i];
        int r = q0 + ty * 4 + i;
#pragma unroll
        for (int j = 0; j < 4; j++)
            ob[(size_t)r * (NH_ * HD_) + h * HD_ + tx * 4 + j] = o_acc[i][j] * invl;
    }
}

// ---------------- Gating: one wave per token ----------------
__global__ __launch_bounds__(64) void gating_kernel(const float* __restrict__ xn2,
                                                    const float* __restrict__ gate_w,
                                                    int* __restrict__ sel,
                                                    float* __restrict__ wt,
                                                    int* __restrict__ counts) {
    int t = blockIdx.x, lane = threadIdx.x;
    const float* x = xn2 + (size_t)t * HID_;
    float logits[E_];
    for (int e = 0; e < E_; e++) {
        float p = 0.f;
        for (int d = lane; d < HID_; d += 64) p += x[d] * gate_w[(size_t)e * HID_ + d];
#pragma unroll
        for (int off = 32; off > 0; off >>= 1) p += __shfl_xor(p, off);
        logits[e] = p;
    }
    float mx = logits[0];
    for (int e = 1; e < E_; e++) mx = fmaxf(mx, logits[e]);
    float pr[E_]; float sum = 0.f;
    for (int e = 0; e < E_; e++) { pr[e] = __expf(logits[e] - mx); sum += pr[e]; }
    int e1 = 0; float p1 = pr[0];
    for (int e = 1; e < E_; e++) if (pr[e] > p1) { p1 = pr[e]; e1 = e; }
    int e2 = -1; float p2 = -1.f;
    for (int e = 0; e < E_; e++) if (e != e1 && pr[e] > p2) { p2 = pr[e]; e2 = e; }
    if (lane == 0) {
        float denom = p1 + p2;
        sel[t * 2] = e1; sel[t * 2 + 1] = e2;
        wt[t * 2] = p1 / denom; wt[t * 2 + 1] = p2 / denom;
        atomicAdd(&counts[e1], 1);
        atomicAdd(&counts[e2], 1);
    }
}

__global__ void init_counts_kernel(int* counts) {
    if (threadIdx.x < E_) counts[threadIdx.x] = 0;
}

__global__ void prefix_kernel(const int* __restrict__ counts, int* __restrict__ ebase,
                              int* __restrict__ cursor) {
    if (threadIdx.x == 0) {
        int b = 0;
        for (int e = 0; e < E_; e++) { ebase[e] = b; cursor[e] = b; b += counts[e]; }
    }
}

__global__ void scatter_kernel(const int* __restrict__ sel, const float* __restrict__ wt,
                               int* __restrict__ cursor, int* __restrict__ tok_list,
                               float* __restrict__ wt_list, int* __restrict__ slot_list) {
    int t = blockIdx.x * blockDim.x + threadIdx.x;
    if (t >= T_) return;
    for (int j = 0; j < 2; j++) {
        int e = sel[t * 2 + j];
        float w = wt[t * 2 + j];
        int p = atomicAdd(&cursor[e], 1);
        tok_list[p] = t;
        wt_list[p] = w;
        slot_list[t * 2 + j] = p;
    }
}

// ---------------- fp32 -> bf16 bulk convert ----------------
__global__ __launch_bounds__(256) void cvt_bf16_kernel(const float* __restrict__ src,
                                                       short* __restrict__ dst, int n8) {
    int stride = gridDim.x * blockDim.x;
    for (int i = blockIdx.x * blockDim.x + threadIdx.x; i < n8; i += stride) {
        float4 a = ((const float4*)src)[2 * i];
        float4 b = ((const float4*)src)[2 * i + 1];
        short8 o;
        o[0] = f2bf(a.x); o[1] = f2bf(a.y); o[2] = f2bf(a.z); o[3] = f2bf(a.w);
        o[4] = f2bf(b.x); o[5] = f2bf(b.y); o[6] = f2bf(b.z); o[7] = f2bf(b.w);
        ((short8*)dst)[i] = o;
    }
}

// cvt wq+wk+wv -> combined wqkvb [1536][1024]; wo -> wob. One launch.
__global__ __launch_bounds__(256) void cvt_attnw_kernel(const float* __restrict__ wq,
                                                        const float* __restrict__ wk,
                                                        const float* __restrict__ wv,
                                                        const float* __restrict__ wo,
                                                        short* __restrict__ wqkvb,
                                                        short* __restrict__ wob) {
    const int NQ = NH_ * HD_ * HID_ / 8;    // 131072
    const int NK = NKV_ * HD_ * HID_ / 8;   // 32768
    const int NO = HID_ * NH_ * HD_ / 8;    // 131072
    int i = blockIdx.x * 256 + threadIdx.x;
    if (i >= NQ + 2 * NK + NO) return;
    const float* s; short* d;
    if (i < NQ)               { s = wq + (size_t)i * 8;                 d = wqkvb + (size_t)i * 8; }
    else if (i < NQ + NK)     { s = wk + (size_t)(i - NQ) * 8;          d = wqkvb + (size_t)i * 8; }
    else if (i < NQ + 2 * NK) { s = wv + (size_t)(i - NQ - NK) * 8;     d = wqkvb + (size_t)i * 8; }
    else                      { s = wo + (size_t)(i - NQ - 2 * NK) * 8; d = wob + (size_t)(i - NQ - 2 * NK) * 8; }
    float4 a = ((const float4*)s)[0];
    float4 b = ((const float4*)s)[1];
    short8 o;
    o[0] = f2bf(a.x); o[1] = f2bf(a.y); o[2] = f2bf(a.z); o[3] = f2bf(a.w);
    o[4] = f2bf(b.x); o[5] = f2bf(b.y); o[6] = f2bf(b.z); o[7] = f2bf(b.w);
    *(short8*)d = o;
}

// cvt two equal-size arrays in one launch (w1, w3)
__global__ __launch_bounds__(256) void cvt2_bf16_kernel(const float* __restrict__ sA,
                                                        short* __restrict__ dA,
                                                        const float* __restrict__ sB,
                                                        short* __restrict__ dB, int n8) {
    int stride = gridDim.x * blockDim.x;
    for (int i = blockIdx.x * blockDim.x + threadIdx.x; i < 2 * n8; i += stride) {
        const float* s; short* d; int j;
        if (i < n8) { s = sA; d = dA; j = i; } else { s = sB; d = dB; j = i - n8; }
        float4 a = ((const float4*)s)[2 * j];
        float4 b = ((const float4*)s)[2 * j + 1];
        short8 o;
        o[0] = f2bf(a.x); o[1] = f2bf(a.y); o[2] = f2bf(a.z); o[3] = f2bf(a.w);
        o[4] = f2bf(b.x); o[5] = f2bf(b.y); o[6] = f2bf(b.z); o[7] = f2bf(b.w);
        ((short8*)d)[j] = o;
    }
}

// ---------------- MoE GEMM 1&3 v2 (+ bank swizzle) ----------------
__global__ __launch_bounds__(256, 2) void moe_gemm13_v2(const short* __restrict__ Xb,
                                                        const short* __restrict__ w1b,
                                                        const short* __restrict__ w3b,
                                                        const int* __restrict__ tok_list,
                                                        const int* __restrict__ ebase,
                                                        const int* __restrict__ counts,
                                                        __hip_bfloat16* __restrict__ h13b) {
    int e = blockIdx.z;
    int cnt = counts[e];
    int bm = blockIdx.y * 128;
    if (cnt <= 0 || bm >= cnt) return;
    int base = ebase[e];
    int bn = blockIdx.x * 128;

    __shared__ alignas(16) short lds[2][3][128 * 32];  // 48 KiB

    int tid = threadIdx.x;
    int sr = tid >> 2;
    int sc = ((tid & 3) * 8) ^ ((sr & 1) << 4);   // swizzled source col
    int ldst = tid * 8;

    int lr0 = bm + sr, lr1 = bm + sr + 64;
    int tok0 = tok_list[base + (lr0 < cnt ? lr0 : cnt - 1)];
    int tok1 = tok_list[base + (lr1 < cnt ? lr1 : cnt - 1)];
    const short* aG0 = Xb + (size_t)tok0 * HID_ + sc;
    const short* aG1 = Xb + (size_t)tok1 * HID_ + sc;
    const short* b1G0 = w1b + (size_t)e * INTER_ * HID_ + (size_t)(bn + sr) * HID_ + sc;
    const short* b1G1 = b1G0 + (size_t)64 * HID_;
    const short* b3G0 = w3b + (size_t)e * INTER_ * HID_ + (size_t)(bn + sr) * HID_ + sc;
    const short* b3G1 = b3G0 + (size_t)64 * HID_;

    int wvid = tid >> 6, lane = tid & 63;
    int wm = (wvid >> 1) * 64, wn = (wvid & 1) * 64;
    int l15 = lane & 15, quad = lane >> 4;
    int rcol = (quad * 8) ^ ((l15 & 1) << 4);

    floatx4 acc1[4][4], acc3[4][4];
#pragma unroll
    for (int i = 0; i < 4; i++)
#pragma unroll
        for (int j = 0; j < 4; j++) { acc1[i][j] = (floatx4)0.f; acc3[i][j] = (floatx4)0.f; }

#define STAGE13(b, k0) do {                                          \
        async_copy16(&lds[b][0][ldst],        aG0 + (k0));           \
        async_copy16(&lds[b][0][ldst + 2048], aG1 + (k0));           \
        async_copy16(&lds[b][1][ldst],        b1G0 + (k0));          \
        async_copy16(&lds[b][1][ldst + 2048], b1G1 + (k0));          \
        async_copy16(&lds[b][2][ldst],        b3G0 + (k0));          \
        async_copy16(&lds[b][2][ldst + 2048], b3G1 + (k0));          \
    } while (0)

    STAGE13(0, 0);
    __syncthreads();

    int cur = 0;
    for (int k0 = 0; k0 < HID_; k0 += 32) {
        if (k0 + 32 < HID_) STAGE13(cur ^ 1, k0 + 32);

        const short* XaR = &lds[cur][0][(wm + l15) * 32 + rcol];
        const short* W1r = &lds[cur][1][(wn + l15) * 32 + rcol];
        const short* W3r = &lds[cur][2][(wn + l15) * 32 + rcol];
        short8 af[4], b1f[4], b3f[4];
#pragma unroll
        for (int i = 0; i < 4; i++) af[i] = *(const short8*)(XaR + i * 16 * 32);
#pragma unroll
        for (int j = 0; j < 4; j++) {
            b1f[j] = *(const short8*)(W1r + j * 16 * 32);
            b3f[j] = *(const short8*)(W3r + j * 16 * 32);
        }
#pragma unroll
        for (int i = 0; i < 4; i++)
#pragma unroll
            for (int j = 0; j < 4; j++) {
                acc1[i][j] = __builtin_amdgcn_mfma_f32_16x16x32_bf16(af[i], b1f[j], acc1[i][j], 0, 0, 0);
                acc3[i][j] = __builtin_amdgcn_mfma_f32_16x16x32_bf16(af[i], b3f[j], acc3[i][j], 0, 0, 0);
            }
        __syncthreads();
        cur ^= 1;
    }
#undef STAGE13

#pragma unroll
    for (int i = 0; i < 4; i++) {
#pragma unroll
        for (int reg = 0; reg < 4; reg++) {
            int lrow = bm + wm + i * 16 + quad * 4 + reg;
            if (lrow >= cnt) continue;
            size_t rowoff = (size_t)(base + lrow) * INTER_;
#pragma unroll
            for (int j = 0; j < 4; j++) {
                float a = acc1[i][j][reg];
                float v = (a / (1.f + __expf(-a))) * acc3[i][j][reg];
                h13b[rowoff + bn + wn + j * 16 + l15] = __float2bfloat16(v);
            }
        }
    }
}

// ---------------- MoE GEMM 2 v4: split-K=4, no atomics (+ bank swizzle) ----------------
__global__ __launch_bounds__(256, 2) void moe_gemm2_v4(const short* __restrict__ h13s,
                                                       const short* __restrict__ w2b,
                                                       const int* __restrict__ ebase,
                                                       const int* __restrict__ counts,
                                                       short* __restrict__ pout) {
    int zz = blockIdx.z;
    int e = zz >> 2, ks = zz & 3;
    int cnt = counts[e];
    int bm = blockIdx.y * 128;
    if (cnt <= 0 || bm >= cnt) return;
    int base = ebase[e];
    int bn = blockIdx.x * 128;
    const int KS = INTER_ / 4;            // 896
    const int K0 = ks * KS;

    __shared__ alignas(16) short lds[2][2][128 * 32];  // 32 KiB

    int tid = threadIdx.x;
    int sr = tid >> 2;
    int sc = ((tid & 3) * 8) ^ ((sr & 1) << 4);
    int ldst = tid * 8;

    int lr0 = bm + sr, lr1 = bm + sr + 64;
    int slot0 = base + (lr0 < cnt ? lr0 : cnt - 1);
    int slot1 = base + (lr1 < cnt ? lr1 : cnt - 1);
    const short* aG0 = h13s + (size_t)slot0 * INTER_ + K0 + sc;
    const short* aG1 = h13s + (size_t)slot1 * INTER_ + K0 + sc;
    const short* bG0 = w2b + (size_t)e * HID_ * INTER_ + (size_t)(bn + sr) * INTER_ + K0 + sc;
    const short* bG1 = bG0 + (size_t)64 * INTER_;

    int wvid = tid >> 6, lane = tid & 63;
    int wm = (wvid >> 1) * 64, wn = (wvid & 1) * 64;
    int l15 = lane & 15, quad = lane >> 4;
    int rcol = (quad * 8) ^ ((l15 & 1) << 4);

    floatx4 acc[4][4];
#pragma unroll
    for (int i = 0; i < 4; i++)
#pragma unroll
        for (int j = 0; j < 4; j++) acc[i][j] = (floatx4)0.f;

#define STAGE2(b, k0) do {                                          \
        async_copy16(&lds[b][0][ldst],        aG0 + (k0));          \
        async_copy16(&lds[b][0][ldst + 2048], aG1 + (k0));          \
        async_copy16(&lds[b][1][ldst],        bG0 + (k0));          \
        async_copy16(&lds[b][1][ldst + 2048], bG1 + (k0));          \
    } while (0)

    STAGE2(0, 0);
    __syncthreads();

    int cur = 0;
    for (int k0 = 0; k0 < KS; k0 += 32) {
        if (k0 + 32 < KS) STAGE2(cur ^ 1, k0 + 32);

        const short* XaR = &lds[cur][0][(wm + l15) * 32 + rcol];
        const short* WsR = &lds[cur][1][(wn + l15) * 32 + rcol];
        short8 af[4], bf_[4];
#pragma unroll
        for (int i = 0; i < 4; i++) af[i] = *(const short8*)(XaR + i * 16 * 32);
#pragma unroll
        for (int j = 0; j < 4; j++) bf_[j] = *(const short8*)(WsR + j * 16 * 32);
#pragma unroll
        for (int i = 0; i < 4; i++)
#pragma unroll
            for (int j = 0; j < 4; j++)
                acc[i][j] = __builtin_amdgcn_mfma_f32_16x16x32_bf16(af[i], bf_[j], acc[i][j], 0, 0, 0);
        __syncthreads();
        cur ^= 1;
    }
#undef STAGE2

#pragma unroll
    for (int i = 0; i < 4; i++) {
#pragma unroll
        for (int reg = 0; reg < 4; reg++) {
            int lrow = bm + wm + i * 16 + quad * 4 + reg;
            if (lrow >= cnt) continue;
            short* prow = pout + ((size_t)ks * (2 * T_) + (base + lrow)) * HID_ + bn + wn;
#pragma unroll
            for (int j = 0; j < 4; j++)
                prow[j * 16 + l15] = f2bf(acc[i][j][reg]);
        }
    }
}

// ---------------- MoE combine ----------------
__global__ __launch_bounds__(256) void moe_combine_kernel(const float* __restrict__ h2,
                                                          const short* __restrict__ pout,
                                                          const int* __restrict__ slot_list,
                                                          const float* __restrict__ wtb,
                                                          float* __restrict__ out) {
    int t = blockIdx.x;
    int d = threadIdx.x * 4;
    float4 r = *(const float4*)(h2 + (size_t)t * HID_ + d);
    int s0 = slot_list[t * 2], s1 = slot_list[t * 2 + 1];
    float w0 = wtb[t * 2], w1 = wtb[t * 2 + 1];
    float m0x = 0.f, m0y = 0.f, m0z = 0.f, m0w = 0.f;
    float m1x = 0.f, m1y = 0.f, m1z = 0.f, m1w = 0.f;
#pragma unroll
    for (int k = 0; k < 4; k++) {
        short4v v0 = *(const short4v*)(pout + ((size_t)k * (2 * T_) + s0) * HID_ + d);
        short4v v1 = *(const short4v*)(pout + ((size_t)k * (2 * T_) + s1) * HID_ + d);
        m0x += bf2f(v0[0]); m0y += bf2f(v0[1]); m0z += bf2f(v0[2]); m0w += bf2f(v0[3]);
        m1x += bf2f(v1[0]); m1y += bf2f(v1[1]); m1z += bf2f(v1[2]); m1w += bf2f(v1[3]);
    }
    r.x += w0 * m0x + w1 * m1x;
    r.y += w0 * m0y + w1 * m1y;
    r.z += w0 * m0z + w1 * m1z;
    r.w += w0 * m0w + w1 * m1w;
    *(float4*)(out + (size_t)t * HID_ + d) = r;
}

// ---------------- Fallback (old) MoE kernels ----------------
__global__ __launch_bounds__(256) void moe_gemm13_mfma(const float* __restrict__ X,
                                                       const float* __restrict__ w1,
                                                       const float* __restrict__ w3,
                                                       const int* __restrict__ tok_list,
                                                       const int* __restrict__ ebase,
                                                       const int* __restrict__ counts,
                                                       __hip_bfloat16* __restrict__ h13b) {
    int e = blockIdx.z;
    int cnt = counts[e];
    int bm = blockIdx.y * 128;
    if (bm >= cnt) return;
    int base = ebase[e];
    int bn = blockIdx.x * 128;

    __shared__ alignas(16) short Xa[128 * 40];
    __shared__ alignas(16) short W1s[128 * 40];
    __shared__ alignas(16) short W3s[128 * 40];

    int tid = threadIdx.x;
    int sr = tid >> 1;
    int scb = (tid & 1) * 16;

    int lrA = bm + sr;
    int tok = (lrA < cnt) ? tok_list[base + lrA] : 0;
    const float* Arow  = X + (size_t)tok * HID_ + scb;
    const float* B1row = w1 + (size_t)e * INTER_ * HID_ + (size_t)(bn + sr) * HID_ + scb;
    const float* B3row = w3 + (size_t)e * INTER_ * HID_ + (size_t)(bn + sr) * HID_ + scb;
    short* XaW = Xa  + sr * 40 + scb;
    short* W1w = W1s + sr * 40 + scb;
    short* W3w = W3s + sr * 40 + scb;

    int wvid = tid >> 6, lane = tid & 63;
    int wm = (wvid >> 1) * 64, wn = (wvid & 1) * 64;
    int l15 = lane & 15, quad = lane >> 4;

    const short* XaR = Xa  + (wm + l15) * 40 + quad * 8;
    const short* W1r = W1s + (wn + l15) * 40 + quad * 8;
    const short* W3r = W3s + (wn + l15) * 40 + quad * 8;

    floatx4 acc1[4][4], acc3[4][4];
#pragma unroll
    for (int i = 0; i < 4; i++)
#pragma unroll
        for (int j = 0; j < 4; j++) { acc1[i][j] = (floatx4)0.f; acc3[i][j] = (floatx4)0.f; }

    for (int k0 = 0; k0 < HID_; k0 += 32) {
        float4 f0 = *(const float4*)(Arow + k0);
        float4 f1 = *(const float4*)(Arow + k0 + 4);
        float4 f2 = *(const float4*)(Arow + k0 + 8);
        float4 f3 = *(const float4*)(Arow + k0 + 12);
        float4 g0 = *(const float4*)(B1row + k0);
        float4 g1 = *(const float4*)(B1row + k0 + 4);
        float4 g2 = *(const float4*)(B1row + k0 + 8);
        float4 g3 = *(const float4*)(B1row + k0 + 12);
        float4 h0 = *(const float4*)(B3row + k0);
        float4 h1 = *(const float4*)(B3row + k0 + 4);
        float4 h2 = *(const float4*)(B3row + k0 + 8);
        float4 h3 = *(const float4*)(B3row + k0 + 12);
        cvt_store16(XaW, f0, f1, f2, f3);
        cvt_store16(W1w, g0, g1, g2, g3);
        cvt_store16(W3w, h0, h1, h2, h3);
        __syncthreads();

        short8 af[4], b1f[4], b3f[4];
#pragma unroll
        for (int i = 0; i < 4; i++) af[i] = *(const short8*)(XaR + i * 16 * 40);
#pragma unroll
        for (int j = 0; j < 4; j++) {
            b1f[j] = *(const short8*)(W1r + j * 16 * 40);
            b3f[j] = *(const short8*)(W3r + j * 16 * 40);
        }
#pragma unroll
        for (int i = 0; i < 4; i++)
#pragma unroll
            for (int j = 0; j < 4; j++) {
                acc1[i][j] = __builtin_amdgcn_mfma_f32_16x16x32_bf16(af[i], b1f[j], acc1[i][j], 0, 0, 0);
                acc3[i][j] = __builtin_amdgcn_mfma_f32_16x16x32_bf16(af[i], b3f[j], acc3[i][j], 0, 0, 0);
            }
        __syncthreads();
    }

#pragma unroll
    for (int i = 0; i < 4; i++) {
#pragma unroll
        for (int reg = 0; reg < 4; reg++) {
            int lrow = bm + wm + i * 16 + quad * 4 + reg;
            if (lrow >= cnt) continue;
            size_t rowoff = (size_t)(base + lrow) * INTER_;
#pragma unroll
            for (int j = 0; j < 4; j++) {
                float a = acc1[i][j][reg];
                float v = (a / (1.f + __expf(-a))) * acc3[i][j][reg];
                h13b[rowoff + bn + wn + j * 16 + l15] = __float2bfloat16(v);
            }
        }
    }
}

__global__ __launch_bounds__(256) void moe_gemm2_mfma(const __hip_bfloat16* __restrict__ h13b,
                                                      const float* __restrict__ w2,
                                                      const int* __restrict__ tok_list,
                                                      const float* __restrict__ wt_list,
                                                      const int* __restrict__ ebase,
                                                      const int* __restrict__ counts,
                                                      float* __restrict__ out) {
    int e = blockIdx.z;
    int cnt = counts[e];
    int bm = blockIdx.y * 128;
    if (bm >= cnt) return;
    int base = ebase[e];
    int bn = blockIdx.x * 128;

    __shared__ alignas(16) short Xa[128 * 40];
    __shared__ alignas(16) short Ws[128 * 40];

    int tid = threadIdx.x;
    int sr = tid >> 1;
    int scb = (tid & 1) * 16;

    int lrA = bm + sr;
    int slot = base + ((lrA < cnt) ? lrA : 0);
    const short* Arow = (const short*)h13b + (size_t)slot * INTER_ + scb;
    const float* Brow = w2 + (size_t)e * HID_ * INTER_ + (size_t)(bn + sr) * INTER_ + scb;
    short* XaW = Xa + sr * 40 + scb;
    short* WsW = Ws + sr * 40 + scb;

    int wvid = tid >> 6, lane = tid & 63;
    int wm = (wvid >> 1) * 64, wn = (wvid & 1) * 64;
    int l15 = lane & 15, quad = lane >> 4;

    const short* XaR = Xa + (wm + l15) * 40 + quad * 8;
    const short* WsR = Ws + (wn + l15) * 40 + quad * 8;

    floatx4 acc[4][4];
#pragma unroll
    for (int i = 0; i < 4; i++)
#pragma unroll
        for (int j = 0; j < 4; j++) acc[i][j] = (floatx4)0.f;

    for (int k0 = 0; k0 < INTER_; k0 += 32) {
        short8 v0 = *(const short8*)(Arow + k0);
        short8 v1 = *(const short8*)(Arow + k0 + 8);
        float4 g0 = *(const float4*)(Brow + k0);
        float4 g1 = *(const float4*)(Brow + k0 + 4);
        float4 g2 = *(const float4*)(Brow + k0 + 8);
        float4 g3 = *(const float4*)(Brow + k0 + 12);
        *(short8*)XaW = v0;
        *(short8*)(XaW + 8) = v1;
        cvt_store16(WsW, g0, g1, g2, g3);
        __syncthreads();

        short8 af[4], bf_[4];
#pragma unroll
        for (int i = 0; i < 4; i++) af[i] = *(const short8*)(XaR + i * 16 * 40);
#pragma unroll
        for (int j = 0; j < 4; j++) bf_[j] = *(const short8*)(WsR + j * 16 * 40);
#pragma unroll
        for (int i = 0; i < 4; i++)
#pragma unroll
            for (int j = 0; j < 4; j++)
                acc[i][j] = __builtin_amdgcn_mfma_f32_16x16x32_bf16(af[i], bf_[j], acc[i][j], 0, 0, 0);
        __syncthreads();
    }

#pragma unroll
    for (int i = 0; i < 4; i++) {
#pragma unroll
        for (int reg = 0; reg < 4; reg++) {
            int lrow = bm + wm + i * 16 + quad * 4 + reg;
            if (lrow >= cnt) continue;
            int tok = tok_list[base + lrow];
            float w = wt_list[base + lrow];
            size_t rowoff = (size_t)tok * HID_;
#pragma unroll
            for (int j = 0; j < 4; j++)
                atomicAdd(&out[rowoff + bn + wn + j * 16 + l15], w * acc[i][j][reg]);
        }
    }
}

__global__ void copy4_kernel(const float* __restrict__ src, float* __restrict__ dst, int n4) {
    int i = blockIdx.x * blockDim.x + threadIdx.x;
    if (i < n4) ((float4*)dst)[i] = ((const float4*)src)[i];
}

extern "C" void kernel_launch(void* const* d_in, const int* in_sizes, int n_in,
                              void* d_out, int out_size, void* d_ws, size_t ws_size,
                              hipStream_t stream) {
    const float* h      = (const float*)d_in[0];
    const int*   pos    = (const int*)d_in[1];
    const float* wq     = (const float*)d_in[2];
    const float* wk     = (const float*)d_in[3];
    const float* wv     = (const float*)d_in[4];
    const float* wo     = (const float*)d_in[5];
    const float* gate_w = (const float*)d_in[6];
    const float* w1     = (const float*)d_in[7];
    const float* w2     = (const float*)d_in[8];
    const float* w3     = (const float*)d_in[9];
    const float* ln1_w  = (const float*)d_in[10];
    const float* ln2_w  = (const float*)d_in[11];
    float* out = (float*)d_out;

    float* ws = (float*)d_ws;
    const size_t M1 = 1024 * 1024;
    // fallback layout (unchanged)
    float* xn1 = ws;                    // 2M (alias ob)
    float* ob  = ws;
    float* qb  = ws + 2 * M1;           // 2M (alias fallback h2)
    float* kb  = ws + 4 * M1;
    float* vb  = ws + 4 * M1 + M1 / 2;
    // big-path layout
    float* qkvb = ws;                   // 3M floats (2048x1536)
    float* xn2 = ws + 5 * M1;           // 2M (both paths)
    __hip_bfloat16* h13b = (__hip_bfloat16*)(ws + 7 * M1);  // ends 14.34M
    float* smallf = ws + 14 * M1 + M1 / 2;
    int*   sel      = (int*)smallf;
    float* wtb      = smallf + 4096;
    int*   counts   = (int*)(smallf + 8192);
    int*   ebase    = (int*)(smallf + 8192 + 16);
    int*   cursor   = (int*)(smallf + 8192 + 32);
    int*   tok_list = (int*)(smallf + 8192 + 64);
    float* wt_list  = smallf + 8192 + 64 + 4352;
    int*   slot_list= (int*)(smallf + 8192 + 64 + 8704);

    const size_t WELEM = (size_t)E_ * INTER_ * HID_;       // 29,360,128
    short* xn2b = (short*)(ws + 15 * M1);                  // 2M shorts
    short* w1bb = (short*)(ws + 16 * M1);                  // WELEM shorts
    short* w3bb = w1bb + WELEM;                            // WELEM shorts
    short* w2bb = w1bb;                                    // reuse after gemm13
    short* pout = w3bb;                                    // 16.8M shorts, fits w3bb (dead after gemm13)
    // pre-MoE bf16 buffers alias w1bb region (all consumed before cvt(w1); stream-ordered)
    short* xn1b  = (short*)(ws + 16 * M1);                 // 2M shorts  (16..17M floats)
    short* wqkvb = (short*)(ws + 17 * M1);                 // 1.5M shorts (17..17.75M)
    short* wob   = (short*)(ws + 17 * M1 + 3 * M1 / 4);    // 1M shorts (17.75..18.25M)
    short* qkvh  = (short*)(ws + 18 * M1 + M1 / 4);        // 3M shorts (18.25..19.75M)
    short* obh   = (short*)(ws + 19 * M1 + 3 * M1 / 4);    // 2M shorts (19.75..20.75M)
    const size_t need_bytes = (16 * M1 + WELEM) * sizeof(float);
    bool big = ws_size >= need_bytes;
    float* h2 = big ? (ws + 3 * M1) : (ws + 2 * M1);       // big: 3..5M; fallback aliases qb

    hipLaunchKernelGGL(init_counts_kernel, dim3(1), dim3(64), 0, stream, counts);

    if (big) {
        hipLaunchKernelGGL(rmsnorm_bf16_kernel, dim3(T_), dim3(256), 0, stream, h, ln1_w, xn1b);
        hipLaunchKernelGGL(cvt_attnw_kernel, dim3(1280), dim3(256), 0, stream, wq, wk, wv, wo, wqkvb, wob);
        hipLaunchKernelGGL(gemm_bf16_v2, dim3(QKVW_ / 128, T_ / 128), dim3(256), 0, stream,
                           xn1b, wqkvb, qkvb, (const float*)nullptr, T_, QKVW_, HID_);
        {
            int tot = T_ * (NH_ + NKV_) * 32;
            hipLaunchKernelGGL(rope_qkv_kernel, dim3((tot + 255) / 256), dim3(256), 0, stream, qkvb, pos);
        }
        hipLaunchKernelGGL(cvt_bf16_kernel, dim3(1536), dim3(256), 0, stream, qkvb, qkvh, T_ * QKVW_ / 8);
        hipLaunchKernelGGL(flash_attn_mfma_c, dim3(32 * 16), dim3(256), 0, stream, qkvh, obh);
        hipLaunchKernelGGL(gemm_bf16_v2, dim3(HID_ / 128, T_ / 128), dim3(256), 0, stream,
                           obh, wob, h2, h, T_, HID_, NH_ * HD_);
        hipLaunchKernelGGL(rmsnorm_dual_kernel, dim3(T_), dim3(256), 0, stream, h2, ln2_w, xn2, xn2b);
    } else {
        hipLaunchKernelGGL(rmsnorm_kernel, dim3(T_), dim3(256), 0, stream, h, ln1_w, xn1);
        hipLaunchKernelGGL(gemm_f32, dim3(16, 32), dim3(256), 0, stream, xn1, wq, qb, (const float*)nullptr, T_, NH_ * HD_, HID_);
        hipLaunchKernelGGL(gemm_f32, dim3(4, 32),  dim3(256), 0, stream, xn1, wk, kb, (const float*)nullptr, T_, NKV_ * HD_, HID_);
        hipLaunchKernelGGL(gemm_f32, dim3(4, 32),  dim3(256), 0, stream, xn1, wv, vb, (const float*)nullptr, T_, NKV_ * HD_, HID_);
        {
            int tot = T_ * (NH_ + NKV_) * 32;
            hipLaunchKernelGGL(rope_kernel, dim3((tot + 255) / 256), dim3(256), 0, stream, qb, kb, pos);
        }
        hipLaunchKernelGGL(flash_attn_kernel, dim3(32 * 16), dim3(256), 0, stream, qb, kb, vb, ob);
        hipLaunchKernelGGL(gemm_f32, dim3(16, 32), dim3(256), 0, stream, ob, wo, h2, h, T_, HID_, NH_ * HD_);
        hipLaunchKernelGGL(rmsnorm_kernel, dim3(T_), dim3(256), 0, stream, h2, ln2_w, xn2);
    }

    hipLaunchKernelGGL(gating_kernel, dim3(T_), dim3(64), 0, stream, xn2, gate_w, sel, wtb, counts);
    hipLaunchKernelGGL(prefix_kernel, dim3(1), dim3(64), 0, stream, counts, ebase, cursor);
    hipLaunchKernelGGL(scatter_kernel, dim3((T_ + 255) / 256), dim3(256), 0, stream, sel, wtb, cursor,
                       tok_list, wt_list, slot_list);

    if (big) {
        const int n8w = (int)(WELEM / 8);
        hipLaunchKernelGGL(cvt2_bf16_kernel, dim3(2048), dim3(256), 0, stream, w1, w1bb, w3, w3bb, n8w);
        hipLaunchKernelGGL(moe_gemm13_v2, dim3(INTER_ / 128, 16, E_), dim3(256), 0, stream,
                           xn2b, w1bb, w3bb, tok_list, ebase, counts, h13b);
        hipLaunchKernelGGL(cvt_bf16_kernel, dim3(2048), dim3(256), 0, stream, w2, w2bb, n8w);
        hipLaunchKernelGGL(moe_gemm2_v4, dim3(HID_ / 128, 16, E_ * 4), dim3(256), 0, stream,
                           (const short*)h13b, w2bb, ebase, counts, pout);
        hipLaunchKernelGGL(moe_combine_kernel, dim3(T_), dim3(256), 0, stream,
                           h2, pout, slot_list, wtb, out);
    } else {
        hipLaunchKernelGGL(moe_gemm13_mfma, dim3(INTER_ / 128, 16, E_), dim3(256), 0, stream,
                           xn2, w1, w3, tok_list, ebase, counts, h13b);
        hipLaunchKernelGGL(copy4_kernel, dim3((T_ * HID_ / 4 + 255) / 256), dim3(256), 0, stream, h2, out, T_ * HID_ / 4);
        hipLaunchKernelGGL(moe_gemm2_mfma, dim3(HID_ / 128, 16, E_), dim3(256), 0, stream,
                           h13b, w2, tok_list, wt_list, ebase, counts, out);
    }
}